// Round 9
// baseline (11114.276 us; speedup 1.0000x reference)
//
#include <hip/hip_runtime.h>
#include <cstdio>

// HardLSTM (2 layers, T=512, B=32, IN=H=1024) on MI355X.
// Round 9: r8 with ONE change — the 64KB A-tile broadcast goes through the
// per-XCD L2 instead of bypassing it. stage64k uses plain cached loads; each
// step a fence(ACQUIRE,"agent") (= buffer_inv: drops clean L1/L2 lines,
// preserves dirty) guarantees freshness of the AGST-published ring data.
// LLC fetch per tile drops from 128x to ~8x (once per XCD). Arithmetic,
// sync, layouts bit-identical to r8 (absmax 4.0 chain preserved).

#define T_STEPS 512
#define DEADLINE_TICKS 6000000ULL   // ~60ms @ 100MHz

typedef __bf16 bf16x8 __attribute__((ext_vector_type(8)));
typedef float  f32x4  __attribute__((ext_vector_type(4)));
typedef unsigned int u32x4 __attribute__((ext_vector_type(4)));
typedef unsigned long long u64;

#define AGLD(p)   __hip_atomic_load((p), __ATOMIC_RELAXED, __HIP_MEMORY_SCOPE_AGENT)
#define AGST(p,v) __hip_atomic_store((p), (v), __ATOMIC_RELAXED, __HIP_MEMORY_SCOPE_AGENT)
#define MFMA16 __builtin_amdgcn_mfma_f32_16x16x32_bf16

__device__ __forceinline__ u64 rtick(){ return __builtin_amdgcn_s_memrealtime(); }

__device__ __forceinline__ unsigned short f2bf(float f){
  union { float f; unsigned u; } v; v.f = f;
  unsigned r = v.u + 0x7FFFu + ((v.u >> 16) & 1u);   // RNE
  return (unsigned short)(r >> 16);
}
__device__ __forceinline__ bf16x8 packbf(f32x4 a, f32x4 b){
  unsigned u0 = f2bf(a[0]) | ((unsigned)f2bf(a[1])<<16);
  unsigned u1 = f2bf(a[2]) | ((unsigned)f2bf(a[3])<<16);
  unsigned u2 = f2bf(b[0]) | ((unsigned)f2bf(b[1])<<16);
  unsigned u3 = f2bf(b[2]) | ((unsigned)f2bf(b[3])<<16);
  u32x4 cv = {u0,u1,u2,u3};
  return __builtin_bit_cast(bf16x8, cv);
}
// frag-layout byte offset of (row 0..31, k8 = k>>3 in 0..127) in a 64KB A-block
__device__ __forceinline__ int fragOff(int row, int k8){
  return ((k8>>2)*2 + (row>>4))*1024 + ((row&15) | ((k8&3)<<4))*16;
}
__device__ __forceinline__ bf16x8 ld_frag_plain(const char* p){
  u32x4 v = *reinterpret_cast<const u32x4*>(p);
  return __builtin_bit_cast(bf16x8, v);
}
__device__ __forceinline__ bf16x8 lds_frag(const char* p){
  u32x4 v = *reinterpret_cast<const u32x4*>(p);
  return __builtin_bit_cast(bf16x8, v);
}

// Stage 64KB global -> LDS with PLAIN cached 16B loads (L2-shared per XCD).
// Caller must fence(ACQUIRE, agent) first. 256 threads x 16 x 16B.
__device__ __forceinline__ void stage64k(const char* src, char* dst, int tid){
  const u32x4* s = reinterpret_cast<const u32x4*>(src) + tid;
  u32x4 r0 = s[0],    r1 = s[256],  r2 = s[512],  r3 = s[768];
  u32x4 r4 = s[1024], r5 = s[1280], r6 = s[1536], r7 = s[1792];
  u32x4 r8 = s[2048], r9 = s[2304], ra = s[2560], rb = s[2816];
  u32x4 rc = s[3072], rd = s[3328], re = s[3584], rf = s[3840];
  u32x4* d = (u32x4*)(dst + tid*16);
  d[0]=r0; d[256]=r1; d[512]=r2; d[768]=r3;
  d[1024]=r4; d[1280]=r5; d[1536]=r6; d[1792]=r7;
  d[2048]=r8; d[2304]=r9; d[2560]=ra; d[2816]=rb;
  d[3072]=rc; d[3328]=rd; d[3584]=re; d[3840]=rf;
}

// Spin until all 128 u16 flags >= tgt. Wave-0 lanes 0..15 each poll 16B (bypass).
__device__ __forceinline__ void spin128(const unsigned short* f, unsigned tgt,
                                        int lane, u64 dl){
  if (lane < 16){
    u64 a = (u64)(uintptr_t)f + (u64)lane*16;
    while (true){
      u32x4 v;
      asm volatile("global_load_dwordx4 %0, %1, off sc0 sc1\n\ts_waitcnt vmcnt(0)"
                   : "=v"(v) : "v"(a) : "memory");
      bool ok = true;
      #pragma unroll
      for (int i=0;i<4;++i){
        unsigned u = v[i];
        ok = ok && ((u & 0xFFFFu) >= tgt) && ((u >> 16) >= tgt);
      }
      if (__all((int)ok)) break;
      if (rtick() > dl) break;
    }
  }
  asm volatile("" ::: "memory");
}

// ---------------- prep kernels ----------------

// x -> Xf: bf16(x+1) in MFMA-A fragment layout, 64KB per step
__global__ void prep_xfrag(const float* __restrict__ x, unsigned short* __restrict__ xf){
  int tid = blockIdx.x*256 + threadIdx.x;      // 2,097,152 total
  int k8 = tid & 127, row = (tid>>7)&31, t = tid>>12;
  const float* s = x + ((size_t)(t*32+row)*1024 + k8*8);
  f32x4 a = *reinterpret_cast<const f32x4*>(s);
  f32x4 b = *reinterpret_cast<const f32x4*>(s+4);
  f32x4 a1 = {a[0]+1.f,a[1]+1.f,a[2]+1.f,a[3]+1.f};
  f32x4 b1 = {b[0]+1.f,b[1]+1.f,b[2]+1.f,b[3]+1.f};
  bf16x8 v = packbf(a1,b1);
  *reinterpret_cast<bf16x8*>((char*)xf + (size_t)t*65536 + fragOff(row,k8)) = v;
}

// h0 -> HiniF (frag layout, both layers)
__global__ void prep_hfrag(const float* __restrict__ h0, unsigned short* __restrict__ hf){
  int tid = blockIdx.x*256 + threadIdx.x;      // 8192 total
  int k8 = tid & 127, row = (tid>>7)&31, L = tid>>12;
  const float* s = h0 + ((size_t)(L*32+row)*1024 + k8*8);
  f32x4 a = *reinterpret_cast<const f32x4*>(s);
  f32x4 b = *reinterpret_cast<const f32x4*>(s+4);
  bf16x8 v = packbf(a,b);
  *reinterpret_cast<bf16x8*>((char*)hf + (size_t)L*65536 + fragOff(row,k8)) = v;
}

__global__ void reduce_mean_f32(const float* __restrict__ src, float* __restrict__ out, float add){
  __shared__ float red[256];
  int t = blockIdx.x, tid = threadIdx.x;
  const float* p = src + (size_t)t*32768;
  float s = 0.f;
  for (int i = tid; i < 32768; i += 256) s += p[i];
  red[tid] = s; __syncthreads();
  for (int o = 128; o > 0; o >>= 1){ if (tid < o) red[tid] += red[tid+o]; __syncthreads(); }
  if (tid == 0) out[t] = red[0]*(1.f/32768.f) + add;
}

__global__ void prep_rs(const float* __restrict__ Wih0, const float* __restrict__ Whh0,
                        const float* __restrict__ Wih1, const float* __restrict__ Whh1,
                        const float* __restrict__ bih0, const float* __restrict__ bhh0,
                        const float* __restrict__ bih1, const float* __restrict__ bhh1,
                        float* __restrict__ rs, float* __restrict__ bias){
  int task = blockIdx.x*4 + (threadIdx.x >> 6);
  int lane = threadIdx.x & 63;
  int L = task >> 12, n = task & 4095;
  const float* pi = (L ? Wih1 : Wih0) + (size_t)n*1024;
  const float* ph = (L ? Whh1 : Whh0) + (size_t)n*1024;
  float s = 0.f;
  #pragma unroll
  for (int e = 0; e < 16; ++e){ int k = lane + e*64; s += pi[k] + ph[k]; }
  #pragma unroll
  for (int m = 32; m; m >>= 1) s += __shfl_xor(s, m);
  if (lane == 0){
    rs[task]   = s;
    bias[task] = (L ? bih1[n] : bih0[n]) + (L ? bhh1[n] : bhh0[n]);
  }
}

// ---------------- recurrent kernel ----------------
// grid 256 x 256. Blocks 0..127: layer 0; 128..255: layer 1 (1 step behind).
// Block bid owns h-cols jb=bid*8 (x4 gates = 32 ncols).
// Wave w: rh=w>>1 (rows rh*16..+15), cg=w&1 (cols jb+cg*4..+3, x4 gates).
__global__ __launch_bounds__(256) void rec8(
    const unsigned short* __restrict__ Xf,     // [512][64KB] frag
    const unsigned short* __restrict__ HiniF,  // [2][64KB] frag
    unsigned short* __restrict__ Ring0,        // [512][32768] frag (y0)
    unsigned short* __restrict__ Ring1,        // [8][32768] frag (h1)
    float* __restrict__ out,
    const float* __restrict__ Wih0, const float* __restrict__ Whh0,
    const float* __restrict__ Wih1, const float* __restrict__ Whh1,
    const float* __restrict__ biasC, const float* __restrict__ rsC,  // [2*4096]
    const float* __restrict__ eps0, const float* __restrict__ c0,
    int* __restrict__ epsP,                    // [512][128]
    unsigned short* __restrict__ flag0,        // 128 u16 (256B)
    unsigned short* __restrict__ flag1)
{
  __shared__ char ldsW[65536];                 // first-half W slice, frag-linear
  __shared__ char ldsA[65536];                 // A-tile (h or y0)
  __shared__ float ldsPs[4];

  const int tid  = threadIdx.x;
  const int lane = tid & 63;
  const int w    = tid >> 6;
  const int L    = blockIdx.x >> 7;
  const int bid  = blockIdx.x & 127;
  const int rh   = w >> 1;
  const int cg   = w & 1;
  const int jb   = bid * 8;
  const int jc   = jb + cg*4;
  const int c    = lane & 15;
  const int q    = c >> 2;
  const int ncol = q*1024 + jc + (c & 3);
  const int koff = (lane >> 4) << 3;
  const u64 dl   = rtick() + DEADLINE_TICKS;

  // chain order per r5: L0 = x-then-h, L1 = h-then-y0.
  const float* Wfirst = L ? Whh1 : Wih0;       // -> LDS (first half of chain)
  const float* Wsec   = L ? Wih1 : Whh0;       // -> VGPR (second half)

  // ---- stage first-half W slice into LDS (fp32->bf16, frag-linear) ----
  for (int i = 0; i < 16; ++i){
    int fi = w*16 + i;                         // 0..63
    int cgx = fi >> 5, kt = fi & 31;
    int nn = q*1024 + jb + cgx*4 + (c & 3);
    const float* src = Wfirst + (size_t)nn*1024 + kt*32 + koff;
    f32x4 wa = *reinterpret_cast<const f32x4*>(src);
    f32x4 wb = *reinterpret_cast<const f32x4*>(src + 4);
    *reinterpret_cast<bf16x8*>(ldsW + fi*1024 + lane*16) = packbf(wa, wb);
  }
  // ---- second-half W into VGPRs ----
  bf16x8 wreg[32];
  {
    const float* src = Wsec + (size_t)ncol*1024 + koff;
    #pragma unroll
    for (int kt = 0; kt < 32; ++kt){
      f32x4 wa = *reinterpret_cast<const f32x4*>(src + kt*32);
      f32x4 wb = *reinterpret_cast<const f32x4*>(src + kt*32 + 4);
      wreg[kt] = packbf(wa, wb);
    }
  }
  __syncthreads();

  const float bia = biasC[L*4096 + ncol];
  const float rsv = rsC[L*4096 + ncol];
  const int jw = jc + (c & 3);
  float creg[4];
  #pragma unroll
  for (int r = 0; r < 4; ++r)
    creg[r] = c0[L*32768 + (rh*16 + (lane>>4)*4 + r)*1024 + jw];

  float* outHn = out + 16777216 + L*32768;
  float* outCn = out + 16777216 + 65536 + L*32768;
  const u64 myFlagA = (u64)(uintptr_t)((L ? flag1 : flag0) + bid);

  for (int t = 0; t < T_STEPS; ++t){
    f32x4 acc = {0.f, 0.f, 0.f, 0.f};
    float et;

    if (L == 0){
      // x-half FIRST (chain start, r5 order) — independent of h
      const char* Ax = (const char*)Xf + (size_t)t*65536;
      #pragma unroll 4
      for (int kt = 0; kt < 32; ++kt){
        bf16x8 a = ld_frag_plain(Ax + (kt*2 + rh)*1024 + lane*16);
        bf16x8 b = lds_frag(ldsW + (cg*32 + kt)*1024 + lane*16);
        acc = MFMA16(a, b, acc, 0, 0, 0);
      }
      et = eps0[t];
      if (w == 0 && t > 0) spin128(flag0, (unsigned)t, lane, dl);
      __syncthreads();
      // drop stale clean L1/L2 lines, then stage through the cache hierarchy
      __builtin_amdgcn_fence(__ATOMIC_ACQUIRE, "agent");
      const char* hsrc = (t == 0) ? (const char*)HiniF
                                  : (const char*)Ring0 + (size_t)(t-1)*65536;
      stage64k(hsrc, ldsA, tid);
      __syncthreads();
      // h-half continues the SAME accumulator chain
      #pragma unroll 4
      for (int kt = 0; kt < 32; ++kt){
        bf16x8 a = lds_frag(ldsA + (kt*2 + rh)*1024 + lane*16);
        acc = MFMA16(a, wreg[kt], acc, 0, 0, 0);
      }
    } else {
      // L1: h-half FIRST (r5 order)
      if (w == 0 && t > 0) spin128(flag1, (unsigned)t, lane, dl);
      __syncthreads();
      __builtin_amdgcn_fence(__ATOMIC_ACQUIRE, "agent");
      const char* hsrc = (t == 0) ? (const char*)HiniF + 65536
                                  : (const char*)Ring1 + (size_t)((t-1)&7)*65536;
      stage64k(hsrc, ldsA, tid);
      __syncthreads();
      #pragma unroll 4
      for (int kt = 0; kt < 32; ++kt){
        bf16x8 a = lds_frag(ldsA + (kt*2 + rh)*1024 + lane*16);
        bf16x8 b = lds_frag(ldsW + (cg*32 + kt)*1024 + lane*16);
        acc = MFMA16(a, b, acc, 0, 0, 0);
      }
      __syncthreads();                         // all waves done reading ldsA
      if (w == 0) spin128(flag0, (unsigned)(t+1), lane, dl);
      __syncthreads();
      __builtin_amdgcn_fence(__ATOMIC_ACQUIRE, "agent");
      // eps1[t] = exact fixed-point sum of 128 partials (bypass loads)
      {
        const u64* ep = reinterpret_cast<const u64*>(epsP + (size_t)t*128);
        u64 v = AGLD(ep + lane);
        int s = (int)(unsigned)v + (int)(unsigned)(v >> 32);
        #pragma unroll
        for (int mm = 32; mm; mm >>= 1) s += __shfl_xor(s, mm);
        et = (float)s * 4.6566128730773926e-10f;   // / (2^16 * 32768)
      }
      stage64k((const char*)Ring0 + (size_t)t*65536, ldsA, tid);
      __syncthreads();
      // y0-half continues the chain
      #pragma unroll 4
      for (int kt = 0; kt < 32; ++kt){
        bf16x8 a = lds_frag(ldsA + (kt*2 + rh)*1024 + lane*16);
        acc = MFMA16(a, wreg[kt], acc, 0, 0, 0);
      }
    }

    // ---- epilogue ----
    char* ringSlot = L ? ((char*)Ring1 + (size_t)(t & 7)*65536)
                       : ((char*)Ring0 + (size_t)t*65536);
    float hyv[4];
    float psum = 0.f;
    #pragma unroll
    for (int r = 0; r < 4; ++r){
      float g  = acc[r] + bia + et*rsv;
      float p4 = __shfl_xor(g, 4), p8 = __shfl_xor(g, 8), p12 = __shfl_xor(p4, 8);
      float iv = (q==0)?g:(q==1)?p4:(q==2)?p8:p12;
      float fv = (q==1)?g:(q==0)?p4:(q==3)?p8:p12;
      float gv = (q==2)?g:(q==3)?p4:(q==0)?p8:p12;
      float ov = (q==3)?g:(q==2)?p4:(q==1)?p8:p12;
      iv = fminf(fmaxf(0.2f*iv + 0.5f, 0.f), 1.f);
      fv = fminf(fmaxf(0.2f*fv + 0.5f, 0.f), 1.f);
      gv = fminf(fmaxf(gv, -1.f), 1.f);
      ov = fminf(fmaxf(0.2f*ov + 0.5f, 0.f), 1.f);
      float cc = fv*(creg[r] + et) + iv*gv;
      creg[r] = cc;
      float hy = ov * fminf(fmaxf(cc, -1.f), 1.f);
      hyv[r] = hy;
      if (c < 4) psum += hy;

      unsigned short hu = f2bf(hy);
      unsigned p2 = (unsigned)hu | (((unsigned)__shfl_xor((int)hu, 1)) << 16);
      unsigned q2 = (unsigned)__shfl_xor((int)p2, 2);
      if (c == 0){
        int sub = (lane>>4)*4 + r;
        size_t bo = (size_t)((jb>>5)*2 + rh)*1024
                  + (size_t)(sub | (((jb>>3)&3)<<4))*16 + (size_t)cg*8;
        AGST(reinterpret_cast<u64*>(ringSlot + bo), (u64)p2 | ((u64)q2 << 32));
      }
    }
    if (L == 0){
      #pragma unroll
      for (int mm = 32; mm; mm >>= 1) psum += __shfl_xor(psum, mm);
      if (lane == 0) ldsPs[w] = psum;
    }
    asm volatile("s_waitcnt vmcnt(0)" ::: "memory");   // drain ring publishes
    __syncthreads();
    if (tid == 0){
      if (L == 0){
        float bs = ldsPs[0] + ldsPs[1] + ldsPs[2] + ldsPs[3];
        AGST(reinterpret_cast<unsigned*>(epsP + (size_t)t*128 + bid),
             (unsigned)(int)llrintf(bs*65536.f));
        asm volatile("s_waitcnt vmcnt(0)" ::: "memory");
      }
      asm volatile("global_store_short %0, %1, off sc0 sc1"
                   :: "v"(myFlagA), "v"((unsigned)(t+1)) : "memory");
    }

    // ---- off-critical-path outputs ----
    if (L){
      #pragma unroll
      for (int r = 0; r < 4; ++r){
        float hy = hyv[r];
        float f1 = __shfl_xor(hy, 1), f2 = __shfl_xor(hy, 2), f3 = __shfl_xor(f1, 2);
        if (c == 0){
          int row = rh*16 + (lane>>4)*4 + r;
          f32x4 o4 = {hy, f1, f2, f3};
          *reinterpret_cast<f32x4*>(out + (size_t)t*32768 + row*1024 + jc) = o4;
        }
      }
    }
    if (t == T_STEPS-1){
      #pragma unroll
      for (int r = 0; r < 4; ++r)
        if (c < 4){
          int row = rh*16 + (lane>>4)*4 + r;
          outHn[row*1024 + jw] = hyv[r];
          outCn[row*1024 + jw] = creg[r];
        }
    }
  }
}

// ---------------- host ----------------

extern "C" void kernel_launch(void* const* d_in, const int* in_sizes, int n_in,
                              void* d_out, int out_size, void* d_ws, size_t ws_size,
                              hipStream_t stream)
{
  const float* x    = (const float*)d_in[0];
  const float* h0   = (const float*)d_in[1];
  const float* c0   = (const float*)d_in[2];
  const float* Wih0 = (const float*)d_in[3];
  const float* Whh0 = (const float*)d_in[4];
  const float* bih0 = (const float*)d_in[5];
  const float* bhh0 = (const float*)d_in[6];
  const float* Wih1 = (const float*)d_in[7];
  const float* Whh1 = (const float*)d_in[8];
  const float* bih1 = (const float*)d_in[9];
  const float* bhh1 = (const float*)d_in[10];
  float* out = (float*)d_out;

  char* ws = (char*)d_ws;
  size_t off = 0;
  auto alloc = [&](size_t bytes)->char* {
    char* p = ws + off; off += (bytes + 255) & ~(size_t)255; return p;
  };
  unsigned short* Xf    = (unsigned short*)alloc((size_t)T_STEPS*65536);   // 32MB
  unsigned short* Ring0 = (unsigned short*)alloc((size_t)T_STEPS*65536);   // 32MB
  unsigned short* Ring1 = (unsigned short*)alloc((size_t)8*65536);         // 512KB
  unsigned short* HiniF = (unsigned short*)alloc(2*65536);
  float* eps0 = (float*)alloc(T_STEPS*4);
  float* bias = (float*)alloc(2*4096*4);
  float* rs   = (float*)alloc(2*4096*4);
  int*   epsP = (int*)alloc((size_t)T_STEPS*128*4);                        // 256KB
  // per-launch-zeroed flags: 2 x 128 u16
  char* sync = alloc(1024);
  unsigned short* flag0 = (unsigned short*)sync;
  unsigned short* flag1 = (unsigned short*)(sync + 512);
  if (off > ws_size)
    fprintf(stderr, "HardLSTM: ws too small, need %zu have %zu\n", off, ws_size);

  hipMemsetAsync(sync, 0, 1024, stream);
  prep_xfrag<<<8192, 256, 0, stream>>>(x, Xf);
  prep_hfrag<<<32, 256, 0, stream>>>(h0, HiniF);
  reduce_mean_f32<<<T_STEPS, 256, 0, stream>>>(x, eps0, 1.0f);  // mean(x_t)+1
  prep_rs<<<2048, 256, 0, stream>>>(Wih0, Whh0, Wih1, Whh1,
                                    bih0, bhh0, bih1, bhh1, rs, bias);

  rec8<<<256, 256, 0, stream>>>(Xf, HiniF, Ring0, Ring1, out,
      Wih0, Whh0, Wih1, Whh1, bias, rs, eps0, c0, epsP, flag0, flag1);
}

// Round 10
// 7597.625 us; speedup vs baseline: 1.4629x; 1.4629x over previous
//
#include <hip/hip_runtime.h>
#include <cstdio>

// HardLSTM (2 layers, T=512, B=32, IN=H=1024) on MI355X.
// Round 10: halve the LLC broadcast and make L2 sharing sound.
//  - W entirely in VGPRs (256 regs: wregF+wregS), __launch_bounds__(256,1).
//    Block = 4 waves x (32 rows x 16 ncols) = 16 h-cols -> 64 blocks/layer.
//  - A-tiles staged with PLAIN CACHED loads; soundness from no-address-reuse
//    (Ring0 & Ring1 both 512 unique slots) + ONE prologue acquire-agent fence
//    (drops stale clean lines from the previous graph replay). No per-step
//    fences (r9 lesson: per-step buffer_inv destroys L2 sharing).
//  - ws fallback: if ws can't fit Ring1[512], use 8 slots + bypass staging.
//  - Arithmetic bit-identical to r8 (same 64-MFMA chain per element).

#define T_STEPS 512
#define DEADLINE_TICKS 6000000ULL   // ~60ms @ 100MHz

typedef __bf16 bf16x8 __attribute__((ext_vector_type(8)));
typedef float  f32x4  __attribute__((ext_vector_type(4)));
typedef unsigned int u32x4 __attribute__((ext_vector_type(4)));
typedef unsigned long long u64;

#define AGLD(p)   __hip_atomic_load((p), __ATOMIC_RELAXED, __HIP_MEMORY_SCOPE_AGENT)
#define AGST(p,v) __hip_atomic_store((p), (v), __ATOMIC_RELAXED, __HIP_MEMORY_SCOPE_AGENT)
#define MFMA16 __builtin_amdgcn_mfma_f32_16x16x32_bf16

__device__ __forceinline__ u64 rtick(){ return __builtin_amdgcn_s_memrealtime(); }

__device__ __forceinline__ unsigned short f2bf(float f){
  union { float f; unsigned u; } v; v.f = f;
  unsigned r = v.u + 0x7FFFu + ((v.u >> 16) & 1u);   // RNE
  return (unsigned short)(r >> 16);
}
__device__ __forceinline__ bf16x8 packbf(f32x4 a, f32x4 b){
  unsigned u0 = f2bf(a[0]) | ((unsigned)f2bf(a[1])<<16);
  unsigned u1 = f2bf(a[2]) | ((unsigned)f2bf(a[3])<<16);
  unsigned u2 = f2bf(b[0]) | ((unsigned)f2bf(b[1])<<16);
  unsigned u3 = f2bf(b[2]) | ((unsigned)f2bf(b[3])<<16);
  u32x4 cv = {u0,u1,u2,u3};
  return __builtin_bit_cast(bf16x8, cv);
}
// frag-layout byte offset of (row 0..31, k8 = k>>3 in 0..127) in a 64KB A-block
__device__ __forceinline__ int fragOff(int row, int k8){
  return ((k8>>2)*2 + (row>>4))*1024 + ((row&15) | ((k8&3)<<4))*16;
}
__device__ __forceinline__ bf16x8 ld_frag_plain(const char* p){
  u32x4 v = *reinterpret_cast<const u32x4*>(p);
  return __builtin_bit_cast(bf16x8, v);
}
__device__ __forceinline__ bf16x8 lds_frag(const char* p){
  u32x4 v = *reinterpret_cast<const u32x4*>(p);
  return __builtin_bit_cast(bf16x8, v);
}

// Stage 64KB global -> LDS, plain cached loads (L2-shared per XCD).
__device__ __forceinline__ void stage64k_c(const char* src, char* dst, int tid){
  const u32x4* s = reinterpret_cast<const u32x4*>(src) + tid;
  u32x4 r0 = s[0],    r1 = s[256],  r2 = s[512],  r3 = s[768];
  u32x4 r4 = s[1024], r5 = s[1280], r6 = s[1536], r7 = s[1792];
  u32x4 r8 = s[2048], r9 = s[2304], ra = s[2560], rb = s[2816];
  u32x4 rc = s[3072], rd = s[3328], re = s[3584], rf = s[3840];
  u32x4* d = (u32x4*)(dst + tid*16);
  d[0]=r0; d[256]=r1; d[512]=r2; d[768]=r3;
  d[1024]=r4; d[1280]=r5; d[1536]=r6; d[1792]=r7;
  d[2048]=r8; d[2304]=r9; d[2560]=ra; d[2816]=rb;
  d[3072]=rc; d[3328]=rd; d[3584]=re; d[3840]=rf;
}
// Stage 64KB global -> LDS, bypass (sc0 sc1) loads — r8-proven fallback path.
__device__ __forceinline__ void stage64k_b(const char* src, char* dst, int tid){
  u32x4 r0,r1,r2,r3,r4,r5,r6,r7,r8,r9,ra,rb,rc,rd,re,rf;
  u64 a = (u64)(uintptr_t)src + (u64)tid*16;
  #define LD(reg, off) asm volatile("global_load_dwordx4 %0, %1, off sc0 sc1" \
                                    : "=v"(reg) : "v"(a + (off)) : "memory")
  LD(r0,0); LD(r1,4096); LD(r2,8192); LD(r3,12288);
  LD(r4,16384); LD(r5,20480); LD(r6,24576); LD(r7,28672);
  LD(r8,32768); LD(r9,36864); LD(ra,40960); LD(rb,45056);
  LD(rc,49152); LD(rd,53248); LD(re,57344); LD(rf,61440);
  #undef LD
  asm volatile("s_waitcnt vmcnt(0)" ::: "memory");
  u32x4* d = (u32x4*)(dst + tid*16);
  d[0]=r0; d[256]=r1; d[512]=r2; d[768]=r3;
  d[1024]=r4; d[1280]=r5; d[1536]=r6; d[1792]=r7;
  d[2048]=r8; d[2304]=r9; d[2560]=ra; d[2816]=rb;
  d[3072]=rc; d[3328]=rd; d[3584]=re; d[3840]=rf;
}

// Spin until all 64 u16 flags >= tgt. Wave lanes 0..7 each poll 16B (bypass).
__device__ __forceinline__ void spin64(const unsigned short* f, unsigned tgt,
                                       int lane, u64 dl){
  if (lane < 8){
    u64 a = (u64)(uintptr_t)f + (u64)lane*16;
    while (true){
      u32x4 v;
      asm volatile("global_load_dwordx4 %0, %1, off sc0 sc1\n\ts_waitcnt vmcnt(0)"
                   : "=v"(v) : "v"(a) : "memory");
      bool ok = true;
      #pragma unroll
      for (int i=0;i<4;++i){
        unsigned u = v[i];
        ok = ok && ((u & 0xFFFFu) >= tgt) && ((u >> 16) >= tgt);
      }
      if (__all((int)ok)) break;
      if (rtick() > dl) break;
    }
  }
  asm volatile("" ::: "memory");
}

// ---------------- prep kernels ----------------

__global__ void prep_xfrag(const float* __restrict__ x, unsigned short* __restrict__ xf){
  int tid = blockIdx.x*256 + threadIdx.x;      // 2,097,152 total
  int k8 = tid & 127, row = (tid>>7)&31, t = tid>>12;
  const float* s = x + ((size_t)(t*32+row)*1024 + k8*8);
  f32x4 a = *reinterpret_cast<const f32x4*>(s);
  f32x4 b = *reinterpret_cast<const f32x4*>(s+4);
  f32x4 a1 = {a[0]+1.f,a[1]+1.f,a[2]+1.f,a[3]+1.f};
  f32x4 b1 = {b[0]+1.f,b[1]+1.f,b[2]+1.f,b[3]+1.f};
  bf16x8 v = packbf(a1,b1);
  *reinterpret_cast<bf16x8*>((char*)xf + (size_t)t*65536 + fragOff(row,k8)) = v;
}

__global__ void prep_hfrag(const float* __restrict__ h0, unsigned short* __restrict__ hf){
  int tid = blockIdx.x*256 + threadIdx.x;      // 8192 total
  int k8 = tid & 127, row = (tid>>7)&31, L = tid>>12;
  const float* s = h0 + ((size_t)(L*32+row)*1024 + k8*8);
  f32x4 a = *reinterpret_cast<const f32x4*>(s);
  f32x4 b = *reinterpret_cast<const f32x4*>(s+4);
  bf16x8 v = packbf(a,b);
  *reinterpret_cast<bf16x8*>((char*)hf + (size_t)L*65536 + fragOff(row,k8)) = v;
}

__global__ void reduce_mean_f32(const float* __restrict__ src, float* __restrict__ out, float add){
  __shared__ float red[256];
  int t = blockIdx.x, tid = threadIdx.x;
  const float* p = src + (size_t)t*32768;
  float s = 0.f;
  for (int i = tid; i < 32768; i += 256) s += p[i];
  red[tid] = s; __syncthreads();
  for (int o = 128; o > 0; o >>= 1){ if (tid < o) red[tid] += red[tid+o]; __syncthreads(); }
  if (tid == 0) out[t] = red[0]*(1.f/32768.f) + add;
}

__global__ void prep_rs(const float* __restrict__ Wih0, const float* __restrict__ Whh0,
                        const float* __restrict__ Wih1, const float* __restrict__ Whh1,
                        const float* __restrict__ bih0, const float* __restrict__ bhh0,
                        const float* __restrict__ bih1, const float* __restrict__ bhh1,
                        float* __restrict__ rs, float* __restrict__ bias){
  int task = blockIdx.x*4 + (threadIdx.x >> 6);
  int lane = threadIdx.x & 63;
  int L = task >> 12, n = task & 4095;
  const float* pi = (L ? Wih1 : Wih0) + (size_t)n*1024;
  const float* ph = (L ? Whh1 : Whh0) + (size_t)n*1024;
  float s = 0.f;
  #pragma unroll
  for (int e = 0; e < 16; ++e){ int k = lane + e*64; s += pi[k] + ph[k]; }
  #pragma unroll
  for (int m = 32; m; m >>= 1) s += __shfl_xor(s, m);
  if (lane == 0){
    rs[task]   = s;
    bias[task] = (L ? bih1[n] : bih0[n]) + (L ? bhh1[n] : bhh0[n]);
  }
}

// ---------------- recurrent kernel ----------------
// grid 128 x 256. Blocks 0..63: layer 0; 64..127: layer 1 (1 step behind).
// Block bid owns h-cols jb=bid*16 (x4 gates = 64 ncols).
// Wave w=cg handles cols jc=jb+w*4 (x4 gates), rows 0..31 via acc0/acc1.
__global__ __launch_bounds__(256, 1) void rec10(
    const unsigned short* __restrict__ Xf,     // [512][64KB] frag
    const unsigned short* __restrict__ HiniF,  // [2][64KB] frag
    unsigned short* __restrict__ Ring0,        // [512][32768] frag (y0)
    unsigned short* __restrict__ Ring1,        // [r1slots][32768] frag (h1)
    int ring1mask, int ring1cached,
    float* __restrict__ out,
    const float* __restrict__ Wih0, const float* __restrict__ Whh0,
    const float* __restrict__ Wih1, const float* __restrict__ Whh1,
    const float* __restrict__ biasC, const float* __restrict__ rsC,  // [2*4096]
    const float* __restrict__ eps0, const float* __restrict__ c0,
    int* __restrict__ epsP,                    // [512][64]
    unsigned short* __restrict__ flag0,        // 64 u16 (128B)
    unsigned short* __restrict__ flag1)
{
  __shared__ char ldsA[65536];                 // A-tile (h or y0)
  __shared__ float ldsPs[4];

  const int tid  = threadIdx.x;
  const int lane = tid & 63;
  const int w    = tid >> 6;                   // = cg, 0..3
  const int L    = blockIdx.x >> 6;
  const int bid  = blockIdx.x & 63;
  const int jb   = bid * 16;
  const int jc   = jb + w*4;
  const int c    = lane & 15;
  const int q    = c >> 2;
  const int ncol = q*1024 + jc + (c & 3);
  const int koff = (lane >> 4) << 3;
  const u64 dl   = rtick() + DEADLINE_TICKS;

  // ONE prologue fence: drop stale clean L1/L2 lines from the previous
  // graph replay. No fences inside the loop (r9 lesson).
  __builtin_amdgcn_fence(__ATOMIC_ACQUIRE, "agent");
  __syncthreads();

  // chain order per r8: L0 = x-then-h, L1 = h-then-y0.
  const float* Wfirst = L ? Whh1 : Wih0;
  const float* Wsec   = L ? Wih1 : Whh0;

  // ---- full W slice into VGPRs (both chain halves) ----
  bf16x8 wregF[32], wregS[32];
  {
    const float* sF = Wfirst + (size_t)ncol*1024 + koff;
    const float* sS = Wsec   + (size_t)ncol*1024 + koff;
    #pragma unroll
    for (int kt = 0; kt < 32; ++kt){
      f32x4 a = *reinterpret_cast<const f32x4*>(sF + kt*32);
      f32x4 b = *reinterpret_cast<const f32x4*>(sF + kt*32 + 4);
      wregF[kt] = packbf(a, b);
      f32x4 cc = *reinterpret_cast<const f32x4*>(sS + kt*32);
      f32x4 d  = *reinterpret_cast<const f32x4*>(sS + kt*32 + 4);
      wregS[kt] = packbf(cc, d);
    }
  }

  const float bia = biasC[L*4096 + ncol];
  const float rsv = rsC[L*4096 + ncol];
  const int jw = jc + (c & 3);
  float creg[2][4];
  #pragma unroll
  for (int m = 0; m < 2; ++m)
    #pragma unroll
    for (int r = 0; r < 4; ++r)
      creg[m][r] = c0[L*32768 + (m*16 + (lane>>4)*4 + r)*1024 + jw];

  float* outHn = out + 16777216 + L*32768;
  float* outCn = out + 16777216 + 65536 + L*32768;
  const u64 myFlagA = (u64)(uintptr_t)((L ? flag1 : flag0) + bid);

  for (int t = 0; t < T_STEPS; ++t){
    f32x4 acc0 = {0.f,0.f,0.f,0.f}, acc1 = {0.f,0.f,0.f,0.f};
    float et;

    if (L == 0){
      // x-half FIRST (chain start) — independent of h, hides the spin
      const char* Ax = (const char*)Xf + (size_t)t*65536;
      #pragma unroll 4
      for (int kt = 0; kt < 32; ++kt){
        bf16x8 a0 = ld_frag_plain(Ax + (kt*2 + 0)*1024 + lane*16);
        bf16x8 a1 = ld_frag_plain(Ax + (kt*2 + 1)*1024 + lane*16);
        acc0 = MFMA16(a0, wregF[kt], acc0, 0, 0, 0);
        acc1 = MFMA16(a1, wregF[kt], acc1, 0, 0, 0);
      }
      et = eps0[t];
      if (w == 0 && t > 0) spin64(flag0, (unsigned)t, lane, dl);
      __syncthreads();
      const char* hsrc = (t == 0) ? (const char*)HiniF
                                  : (const char*)Ring0 + (size_t)(t-1)*65536;
      stage64k_c(hsrc, ldsA, tid);               // cached: once per XCD
      __syncthreads();
      #pragma unroll 4
      for (int kt = 0; kt < 32; ++kt){
        bf16x8 a0 = lds_frag(ldsA + (kt*2 + 0)*1024 + lane*16);
        bf16x8 a1 = lds_frag(ldsA + (kt*2 + 1)*1024 + lane*16);
        acc0 = MFMA16(a0, wregS[kt], acc0, 0, 0, 0);
        acc1 = MFMA16(a1, wregS[kt], acc1, 0, 0, 0);
      }
    } else {
      // L1: h-half FIRST
      if (w == 0 && t > 0) spin64(flag1, (unsigned)t, lane, dl);
      __syncthreads();
      const char* hsrc = (t == 0) ? (const char*)HiniF + 65536
                                  : (const char*)Ring1 + (size_t)((t-1) & ring1mask)*65536;
      if (t == 0 || ring1cached) stage64k_c(hsrc, ldsA, tid);
      else                       stage64k_b(hsrc, ldsA, tid);
      __syncthreads();
      #pragma unroll 4
      for (int kt = 0; kt < 32; ++kt){
        bf16x8 a0 = lds_frag(ldsA + (kt*2 + 0)*1024 + lane*16);
        bf16x8 a1 = lds_frag(ldsA + (kt*2 + 1)*1024 + lane*16);
        acc0 = MFMA16(a0, wregF[kt], acc0, 0, 0, 0);
        acc1 = MFMA16(a1, wregF[kt], acc1, 0, 0, 0);
      }
      __syncthreads();                           // all waves done with ldsA
      if (w == 0) spin64(flag0, (unsigned)(t+1), lane, dl);
      __syncthreads();
      // eps1[t] = exact fixed-point sum of 64 partials (bypass loads)
      {
        int s = 0;
        const u64* ep = reinterpret_cast<const u64*>(epsP + (size_t)t*64);
        if (lane < 32){
          u64 v = AGLD(ep + lane);
          s = (int)(unsigned)v + (int)(unsigned)(v >> 32);
        }
        #pragma unroll
        for (int mm = 32; mm; mm >>= 1) s += __shfl_xor(s, mm);
        et = (float)s * 4.6566128730773926e-10f;   // / (2^16 * 32768)
      }
      stage64k_c((const char*)Ring0 + (size_t)t*65536, ldsA, tid);
      __syncthreads();
      #pragma unroll 4
      for (int kt = 0; kt < 32; ++kt){
        bf16x8 a0 = lds_frag(ldsA + (kt*2 + 0)*1024 + lane*16);
        bf16x8 a1 = lds_frag(ldsA + (kt*2 + 1)*1024 + lane*16);
        acc0 = MFMA16(a0, wregS[kt], acc0, 0, 0, 0);
        acc1 = MFMA16(a1, wregS[kt], acc1, 0, 0, 0);
      }
    }

    // ---- epilogue ----
    char* ringSlot = L ? ((char*)Ring1 + (size_t)(t & ring1mask)*65536)
                       : ((char*)Ring0 + (size_t)t*65536);
    float hyv[2][4];
    float psum = 0.f;
    #pragma unroll
    for (int m = 0; m < 2; ++m){
      f32x4 av = m ? acc1 : acc0;
      #pragma unroll
      for (int r = 0; r < 4; ++r){
        float g  = av[r] + bia + et*rsv;
        float p4 = __shfl_xor(g, 4), p8 = __shfl_xor(g, 8), p12 = __shfl_xor(p4, 8);
        float iv = (q==0)?g:(q==1)?p4:(q==2)?p8:p12;
        float fv = (q==1)?g:(q==0)?p4:(q==3)?p8:p12;
        float gv = (q==2)?g:(q==3)?p4:(q==0)?p8:p12;
        float ov = (q==3)?g:(q==2)?p4:(q==1)?p8:p12;
        iv = fminf(fmaxf(0.2f*iv + 0.5f, 0.f), 1.f);
        fv = fminf(fmaxf(0.2f*fv + 0.5f, 0.f), 1.f);
        gv = fminf(fmaxf(gv, -1.f), 1.f);
        ov = fminf(fmaxf(0.2f*ov + 0.5f, 0.f), 1.f);
        float cc = fv*(creg[m][r] + et) + iv*gv;
        creg[m][r] = cc;
        float hy = ov * fminf(fmaxf(cc, -1.f), 1.f);
        hyv[m][r] = hy;
        if (c < 4) psum += hy;

        unsigned short hu = f2bf(hy);
        unsigned p2 = (unsigned)hu | (((unsigned)__shfl_xor((int)hu, 1)) << 16);
        unsigned q2 = (unsigned)__shfl_xor((int)p2, 2);
        if (c == 0){
          int sub = (lane>>4)*4 + r;
          size_t bo = (size_t)((jc>>5)*2 + m)*1024
                    + (size_t)(sub | (((jc>>3)&3)<<4))*16 + (size_t)(jc&7)*2;
          AGST(reinterpret_cast<u64*>(ringSlot + bo), (u64)p2 | ((u64)q2 << 32));
        }
      }
    }
    if (L == 0){
      #pragma unroll
      for (int mm = 32; mm; mm >>= 1) psum += __shfl_xor(psum, mm);
      if (lane == 0) ldsPs[w] = psum;
    }
    asm volatile("s_waitcnt vmcnt(0)" ::: "memory");   // drain ring publishes
    __syncthreads();
    if (tid == 0){
      if (L == 0){
        float bs = ldsPs[0] + ldsPs[1] + ldsPs[2] + ldsPs[3];
        AGST(reinterpret_cast<unsigned*>(epsP + (size_t)t*64 + bid),
             (unsigned)(int)llrintf(bs*65536.f));
        asm volatile("s_waitcnt vmcnt(0)" ::: "memory");
      }
      asm volatile("global_store_short %0, %1, off sc0 sc1"
                   :: "v"(myFlagA), "v"((unsigned)(t+1)) : "memory");
    }

    // ---- off-critical-path outputs ----
    if (L){
      #pragma unroll
      for (int m = 0; m < 2; ++m)
        #pragma unroll
        for (int r = 0; r < 4; ++r){
          float hy = hyv[m][r];
          float f1 = __shfl_xor(hy, 1), f2 = __shfl_xor(hy, 2), f3 = __shfl_xor(f1, 2);
          if (c == 0){
            int row = m*16 + (lane>>4)*4 + r;
            f32x4 o4 = {hy, f1, f2, f3};
            *reinterpret_cast<f32x4*>(out + (size_t)t*32768 + row*1024 + jc) = o4;
          }
        }
    }
    if (t == T_STEPS-1){
      #pragma unroll
      for (int m = 0; m < 2; ++m)
        #pragma unroll
        for (int r = 0; r < 4; ++r)
          if (c < 4){
            int row = m*16 + (lane>>4)*4 + r;
            outHn[row*1024 + jw] = hyv[m][r];
            outCn[row*1024 + jw] = creg[m][r];
          }
    }
  }
}

// ---------------- host ----------------

extern "C" void kernel_launch(void* const* d_in, const int* in_sizes, int n_in,
                              void* d_out, int out_size, void* d_ws, size_t ws_size,
                              hipStream_t stream)
{
  const float* x    = (const float*)d_in[0];
  const float* h0   = (const float*)d_in[1];
  const float* c0   = (const float*)d_in[2];
  const float* Wih0 = (const float*)d_in[3];
  const float* Whh0 = (const float*)d_in[4];
  const float* bih0 = (const float*)d_in[5];
  const float* bhh0 = (const float*)d_in[6];
  const float* Wih1 = (const float*)d_in[7];
  const float* Whh1 = (const float*)d_in[8];
  const float* bih1 = (const float*)d_in[9];
  const float* bhh1 = (const float*)d_in[10];
  float* out = (float*)d_out;

  char* ws = (char*)d_ws;
  size_t off = 0;
  auto alloc = [&](size_t bytes)->char* {
    char* p = ws + off; off += (bytes + 255) & ~(size_t)255; return p;
  };
  unsigned short* Xf    = (unsigned short*)alloc((size_t)T_STEPS*65536);   // 32MB
  unsigned short* Ring0 = (unsigned short*)alloc((size_t)T_STEPS*65536);   // 32MB
  unsigned short* HiniF = (unsigned short*)alloc(2*65536);
  float* eps0 = (float*)alloc(T_STEPS*4);
  float* bias = (float*)alloc(2*4096*4);
  float* rs   = (float*)alloc(2*4096*4);
  int*   epsP = (int*)alloc((size_t)T_STEPS*64*4);                         // 128KB
  char* sync  = alloc(512);                       // flag0 (128B) + flag1 (128B)
  unsigned short* flag0 = (unsigned short*)sync;
  unsigned short* flag1 = (unsigned short*)(sync + 128);
  // Ring1: prefer 512 unique slots (cached staging); fall back to 8 + bypass.
  size_t remain  = (off <= ws_size) ? (ws_size - off) : 0;
  int r1slots    = (remain >= (size_t)(T_STEPS+1)*65536) ? T_STEPS : 8;
  unsigned short* Ring1 = (unsigned short*)alloc((size_t)r1slots*65536);
  int r1mask   = r1slots - 1;
  int r1cached = (r1slots == T_STEPS) ? 1 : 0;
  if (off > ws_size)
    fprintf(stderr, "HardLSTM: ws too small, need %zu have %zu\n", off, ws_size);

  hipMemsetAsync(sync, 0, 512, stream);
  prep_xfrag<<<8192, 256, 0, stream>>>(x, Xf);
  prep_hfrag<<<32, 256, 0, stream>>>(h0, HiniF);
  reduce_mean_f32<<<T_STEPS, 256, 0, stream>>>(x, eps0, 1.0f);  // mean(x_t)+1
  prep_rs<<<2048, 256, 0, stream>>>(Wih0, Whh0, Wih1, Whh1,
                                    bih0, bhh0, bih1, bhh1, rs, bias);

  rec10<<<128, 256, 0, stream>>>(Xf, HiniF, Ring0, Ring1, r1mask, r1cached, out,
      Wih0, Whh0, Wih1, Whh1, bias, rs, eps0, c0, epsP, flag0, flag1);
}

// Round 11
// 6631.374 us; speedup vs baseline: 1.6760x; 1.1457x over previous
//
#include <hip/hip_runtime.h>
#include <cstdio>

// HardLSTM (2 layers, T=512, B=32, IN=H=1024) on MI355X.
// Round 11: ONE change vs r10 — fully unroll (#pragma unroll, 32x) every kt
// loop that indexes wregF[]/wregS[]. r10's `#pragma unroll 4` left those
// ext_vector arrays runtime-indexed -> scratch (VGPR_Count=88 proved it),
// and every MFMA operand read became a 16B scratch global load: 256KB per
// block-step -> the 5.3GB FETCH_SIZE and the r8-r10 plateau. With full
// unroll the W slice is register-resident (~300 VGPRs, budget 512 at
// __launch_bounds__(256,1)). Everything else identical to r10.

#define T_STEPS 512
#define DEADLINE_TICKS 6000000ULL   // ~60ms @ 100MHz

typedef __bf16 bf16x8 __attribute__((ext_vector_type(8)));
typedef float  f32x4  __attribute__((ext_vector_type(4)));
typedef unsigned int u32x4 __attribute__((ext_vector_type(4)));
typedef unsigned long long u64;

#define AGLD(p)   __hip_atomic_load((p), __ATOMIC_RELAXED, __HIP_MEMORY_SCOPE_AGENT)
#define AGST(p,v) __hip_atomic_store((p), (v), __ATOMIC_RELAXED, __HIP_MEMORY_SCOPE_AGENT)
#define MFMA16 __builtin_amdgcn_mfma_f32_16x16x32_bf16

__device__ __forceinline__ u64 rtick(){ return __builtin_amdgcn_s_memrealtime(); }

__device__ __forceinline__ unsigned short f2bf(float f){
  union { float f; unsigned u; } v; v.f = f;
  unsigned r = v.u + 0x7FFFu + ((v.u >> 16) & 1u);   // RNE
  return (unsigned short)(r >> 16);
}
__device__ __forceinline__ bf16x8 packbf(f32x4 a, f32x4 b){
  unsigned u0 = f2bf(a[0]) | ((unsigned)f2bf(a[1])<<16);
  unsigned u1 = f2bf(a[2]) | ((unsigned)f2bf(a[3])<<16);
  unsigned u2 = f2bf(b[0]) | ((unsigned)f2bf(b[1])<<16);
  unsigned u3 = f2bf(b[2]) | ((unsigned)f2bf(b[3])<<16);
  u32x4 cv = {u0,u1,u2,u3};
  return __builtin_bit_cast(bf16x8, cv);
}
// frag-layout byte offset of (row 0..31, k8 = k>>3 in 0..127) in a 64KB A-block
__device__ __forceinline__ int fragOff(int row, int k8){
  return ((k8>>2)*2 + (row>>4))*1024 + ((row&15) | ((k8&3)<<4))*16;
}
__device__ __forceinline__ bf16x8 ld_frag_plain(const char* p){
  u32x4 v = *reinterpret_cast<const u32x4*>(p);
  return __builtin_bit_cast(bf16x8, v);
}
__device__ __forceinline__ bf16x8 lds_frag(const char* p){
  u32x4 v = *reinterpret_cast<const u32x4*>(p);
  return __builtin_bit_cast(bf16x8, v);
}

// Stage 64KB global -> LDS, plain cached loads (L2-shared per XCD).
__device__ __forceinline__ void stage64k_c(const char* src, char* dst, int tid){
  const u32x4* s = reinterpret_cast<const u32x4*>(src) + tid;
  u32x4 r0 = s[0],    r1 = s[256],  r2 = s[512],  r3 = s[768];
  u32x4 r4 = s[1024], r5 = s[1280], r6 = s[1536], r7 = s[1792];
  u32x4 r8 = s[2048], r9 = s[2304], ra = s[2560], rb = s[2816];
  u32x4 rc = s[3072], rd = s[3328], re = s[3584], rf = s[3840];
  u32x4* d = (u32x4*)(dst + tid*16);
  d[0]=r0; d[256]=r1; d[512]=r2; d[768]=r3;
  d[1024]=r4; d[1280]=r5; d[1536]=r6; d[1792]=r7;
  d[2048]=r8; d[2304]=r9; d[2560]=ra; d[2816]=rb;
  d[3072]=rc; d[3328]=rd; d[3584]=re; d[3840]=rf;
}
// Stage 64KB global -> LDS, bypass (sc0 sc1) loads — r8-proven fallback path.
__device__ __forceinline__ void stage64k_b(const char* src, char* dst, int tid){
  u32x4 r0,r1,r2,r3,r4,r5,r6,r7,r8,r9,ra,rb,rc,rd,re,rf;
  u64 a = (u64)(uintptr_t)src + (u64)tid*16;
  #define LD(reg, off) asm volatile("global_load_dwordx4 %0, %1, off sc0 sc1" \
                                    : "=v"(reg) : "v"(a + (off)) : "memory")
  LD(r0,0); LD(r1,4096); LD(r2,8192); LD(r3,12288);
  LD(r4,16384); LD(r5,20480); LD(r6,24576); LD(r7,28672);
  LD(r8,32768); LD(r9,36864); LD(ra,40960); LD(rb,45056);
  LD(rc,49152); LD(rd,53248); LD(re,57344); LD(rf,61440);
  #undef LD
  asm volatile("s_waitcnt vmcnt(0)" ::: "memory");
  u32x4* d = (u32x4*)(dst + tid*16);
  d[0]=r0; d[256]=r1; d[512]=r2; d[768]=r3;
  d[1024]=r4; d[1280]=r5; d[1536]=r6; d[1792]=r7;
  d[2048]=r8; d[2304]=r9; d[2560]=ra; d[2816]=rb;
  d[3072]=rc; d[3328]=rd; d[3584]=re; d[3840]=rf;
}

// Spin until all 64 u16 flags >= tgt. Wave lanes 0..7 each poll 16B (bypass).
__device__ __forceinline__ void spin64(const unsigned short* f, unsigned tgt,
                                       int lane, u64 dl){
  if (lane < 8){
    u64 a = (u64)(uintptr_t)f + (u64)lane*16;
    while (true){
      u32x4 v;
      asm volatile("global_load_dwordx4 %0, %1, off sc0 sc1\n\ts_waitcnt vmcnt(0)"
                   : "=v"(v) : "v"(a) : "memory");
      bool ok = true;
      #pragma unroll
      for (int i=0;i<4;++i){
        unsigned u = v[i];
        ok = ok && ((u & 0xFFFFu) >= tgt) && ((u >> 16) >= tgt);
      }
      if (__all((int)ok)) break;
      if (rtick() > dl) break;
    }
  }
  asm volatile("" ::: "memory");
}

// ---------------- prep kernels ----------------

__global__ void prep_xfrag(const float* __restrict__ x, unsigned short* __restrict__ xf){
  int tid = blockIdx.x*256 + threadIdx.x;      // 2,097,152 total
  int k8 = tid & 127, row = (tid>>7)&31, t = tid>>12;
  const float* s = x + ((size_t)(t*32+row)*1024 + k8*8);
  f32x4 a = *reinterpret_cast<const f32x4*>(s);
  f32x4 b = *reinterpret_cast<const f32x4*>(s+4);
  f32x4 a1 = {a[0]+1.f,a[1]+1.f,a[2]+1.f,a[3]+1.f};
  f32x4 b1 = {b[0]+1.f,b[1]+1.f,b[2]+1.f,b[3]+1.f};
  bf16x8 v = packbf(a1,b1);
  *reinterpret_cast<bf16x8*>((char*)xf + (size_t)t*65536 + fragOff(row,k8)) = v;
}

__global__ void prep_hfrag(const float* __restrict__ h0, unsigned short* __restrict__ hf){
  int tid = blockIdx.x*256 + threadIdx.x;      // 8192 total
  int k8 = tid & 127, row = (tid>>7)&31, L = tid>>12;
  const float* s = h0 + ((size_t)(L*32+row)*1024 + k8*8);
  f32x4 a = *reinterpret_cast<const f32x4*>(s);
  f32x4 b = *reinterpret_cast<const f32x4*>(s+4);
  bf16x8 v = packbf(a,b);
  *reinterpret_cast<bf16x8*>((char*)hf + (size_t)L*65536 + fragOff(row,k8)) = v;
}

__global__ void reduce_mean_f32(const float* __restrict__ src, float* __restrict__ out, float add){
  __shared__ float red[256];
  int t = blockIdx.x, tid = threadIdx.x;
  const float* p = src + (size_t)t*32768;
  float s = 0.f;
  for (int i = tid; i < 32768; i += 256) s += p[i];
  red[tid] = s; __syncthreads();
  for (int o = 128; o > 0; o >>= 1){ if (tid < o) red[tid] += red[tid+o]; __syncthreads(); }
  if (tid == 0) out[t] = red[0]*(1.f/32768.f) + add;
}

__global__ void prep_rs(const float* __restrict__ Wih0, const float* __restrict__ Whh0,
                        const float* __restrict__ Wih1, const float* __restrict__ Whh1,
                        const float* __restrict__ bih0, const float* __restrict__ bhh0,
                        const float* __restrict__ bih1, const float* __restrict__ bhh1,
                        float* __restrict__ rs, float* __restrict__ bias){
  int task = blockIdx.x*4 + (threadIdx.x >> 6);
  int lane = threadIdx.x & 63;
  int L = task >> 12, n = task & 4095;
  const float* pi = (L ? Wih1 : Wih0) + (size_t)n*1024;
  const float* ph = (L ? Whh1 : Whh0) + (size_t)n*1024;
  float s = 0.f;
  #pragma unroll
  for (int e = 0; e < 16; ++e){ int k = lane + e*64; s += pi[k] + ph[k]; }
  #pragma unroll
  for (int m = 32; m; m >>= 1) s += __shfl_xor(s, m);
  if (lane == 0){
    rs[task]   = s;
    bias[task] = (L ? bih1[n] : bih0[n]) + (L ? bhh1[n] : bhh0[n]);
  }
}

// ---------------- recurrent kernel ----------------
// grid 128 x 256. Blocks 0..63: layer 0; 64..127: layer 1 (1 step behind).
// Block bid owns h-cols jb=bid*16 (x4 gates = 64 ncols).
// Wave w=cg handles cols jc=jb+w*4 (x4 gates), rows 0..31 via acc0/acc1.
__global__ __launch_bounds__(256, 1) void rec11(
    const unsigned short* __restrict__ Xf,     // [512][64KB] frag
    const unsigned short* __restrict__ HiniF,  // [2][64KB] frag
    unsigned short* __restrict__ Ring0,        // [512][32768] frag (y0)
    unsigned short* __restrict__ Ring1,        // [r1slots][32768] frag (h1)
    int ring1mask, int ring1cached,
    float* __restrict__ out,
    const float* __restrict__ Wih0, const float* __restrict__ Whh0,
    const float* __restrict__ Wih1, const float* __restrict__ Whh1,
    const float* __restrict__ biasC, const float* __restrict__ rsC,  // [2*4096]
    const float* __restrict__ eps0, const float* __restrict__ c0,
    int* __restrict__ epsP,                    // [512][64]
    unsigned short* __restrict__ flag0,        // 64 u16 (128B)
    unsigned short* __restrict__ flag1)
{
  __shared__ char ldsA[65536];                 // A-tile (h or y0)
  __shared__ float ldsPs[4];

  const int tid  = threadIdx.x;
  const int lane = tid & 63;
  const int w    = tid >> 6;                   // = cg, 0..3
  const int L    = blockIdx.x >> 6;
  const int bid  = blockIdx.x & 63;
  const int jb   = bid * 16;
  const int jc   = jb + w*4;
  const int c    = lane & 15;
  const int q    = c >> 2;
  const int ncol = q*1024 + jc + (c & 3);
  const int koff = (lane >> 4) << 3;
  const u64 dl   = rtick() + DEADLINE_TICKS;

  // ONE prologue fence: drop stale clean L1/L2 lines from the previous
  // graph replay. No fences inside the loop (r9 lesson).
  __builtin_amdgcn_fence(__ATOMIC_ACQUIRE, "agent");
  __syncthreads();

  // chain order per r8: L0 = x-then-h, L1 = h-then-y0.
  const float* Wfirst = L ? Whh1 : Wih0;
  const float* Wsec   = L ? Wih1 : Whh0;

  // ---- full W slice into VGPRs (both chain halves) ----
  // NOTE rule #20: every loop touching wregF/wregS MUST be fully unrolled,
  // otherwise the arrays are demoted to scratch (r10: VGPR=88, 5.3GB FETCH).
  bf16x8 wregF[32], wregS[32];
  {
    const float* sF = Wfirst + (size_t)ncol*1024 + koff;
    const float* sS = Wsec   + (size_t)ncol*1024 + koff;
    #pragma unroll
    for (int kt = 0; kt < 32; ++kt){
      f32x4 a = *reinterpret_cast<const f32x4*>(sF + kt*32);
      f32x4 b = *reinterpret_cast<const f32x4*>(sF + kt*32 + 4);
      wregF[kt] = packbf(a, b);
      f32x4 cc = *reinterpret_cast<const f32x4*>(sS + kt*32);
      f32x4 d  = *reinterpret_cast<const f32x4*>(sS + kt*32 + 4);
      wregS[kt] = packbf(cc, d);
    }
  }

  const float bia = biasC[L*4096 + ncol];
  const float rsv = rsC[L*4096 + ncol];
  const int jw = jc + (c & 3);
  float creg[2][4];
  #pragma unroll
  for (int m = 0; m < 2; ++m)
    #pragma unroll
    for (int r = 0; r < 4; ++r)
      creg[m][r] = c0[L*32768 + (m*16 + (lane>>4)*4 + r)*1024 + jw];

  float* outHn = out + 16777216 + L*32768;
  float* outCn = out + 16777216 + 65536 + L*32768;
  const u64 myFlagA = (u64)(uintptr_t)((L ? flag1 : flag0) + bid);

  for (int t = 0; t < T_STEPS; ++t){
    f32x4 acc0 = {0.f,0.f,0.f,0.f}, acc1 = {0.f,0.f,0.f,0.f};
    float et;

    if (L == 0){
      // x-half FIRST (chain start) — independent of h, hides the spin
      const char* Ax = (const char*)Xf + (size_t)t*65536;
      #pragma unroll
      for (int kt = 0; kt < 32; ++kt){
        bf16x8 a0 = ld_frag_plain(Ax + (kt*2 + 0)*1024 + lane*16);
        bf16x8 a1 = ld_frag_plain(Ax + (kt*2 + 1)*1024 + lane*16);
        acc0 = MFMA16(a0, wregF[kt], acc0, 0, 0, 0);
        acc1 = MFMA16(a1, wregF[kt], acc1, 0, 0, 0);
      }
      et = eps0[t];
      if (w == 0 && t > 0) spin64(flag0, (unsigned)t, lane, dl);
      __syncthreads();
      const char* hsrc = (t == 0) ? (const char*)HiniF
                                  : (const char*)Ring0 + (size_t)(t-1)*65536;
      stage64k_c(hsrc, ldsA, tid);               // cached: once per XCD
      __syncthreads();
      #pragma unroll
      for (int kt = 0; kt < 32; ++kt){
        bf16x8 a0 = lds_frag(ldsA + (kt*2 + 0)*1024 + lane*16);
        bf16x8 a1 = lds_frag(ldsA + (kt*2 + 1)*1024 + lane*16);
        acc0 = MFMA16(a0, wregS[kt], acc0, 0, 0, 0);
        acc1 = MFMA16(a1, wregS[kt], acc1, 0, 0, 0);
      }
    } else {
      // L1: h-half FIRST
      if (w == 0 && t > 0) spin64(flag1, (unsigned)t, lane, dl);
      __syncthreads();
      const char* hsrc = (t == 0) ? (const char*)HiniF + 65536
                                  : (const char*)Ring1 + (size_t)((t-1) & ring1mask)*65536;
      if (t == 0 || ring1cached) stage64k_c(hsrc, ldsA, tid);
      else                       stage64k_b(hsrc, ldsA, tid);
      __syncthreads();
      #pragma unroll
      for (int kt = 0; kt < 32; ++kt){
        bf16x8 a0 = lds_frag(ldsA + (kt*2 + 0)*1024 + lane*16);
        bf16x8 a1 = lds_frag(ldsA + (kt*2 + 1)*1024 + lane*16);
        acc0 = MFMA16(a0, wregF[kt], acc0, 0, 0, 0);
        acc1 = MFMA16(a1, wregF[kt], acc1, 0, 0, 0);
      }
      __syncthreads();                           // all waves done with ldsA
      if (w == 0) spin64(flag0, (unsigned)(t+1), lane, dl);
      __syncthreads();
      // eps1[t] = exact fixed-point sum of 64 partials (bypass loads)
      {
        int s = 0;
        const u64* ep = reinterpret_cast<const u64*>(epsP + (size_t)t*64);
        if (lane < 32){
          u64 v = AGLD(ep + lane);
          s = (int)(unsigned)v + (int)(unsigned)(v >> 32);
        }
        #pragma unroll
        for (int mm = 32; mm; mm >>= 1) s += __shfl_xor(s, mm);
        et = (float)s * 4.6566128730773926e-10f;   // / (2^16 * 32768)
      }
      stage64k_c((const char*)Ring0 + (size_t)t*65536, ldsA, tid);
      __syncthreads();
      #pragma unroll
      for (int kt = 0; kt < 32; ++kt){
        bf16x8 a0 = lds_frag(ldsA + (kt*2 + 0)*1024 + lane*16);
        bf16x8 a1 = lds_frag(ldsA + (kt*2 + 1)*1024 + lane*16);
        acc0 = MFMA16(a0, wregS[kt], acc0, 0, 0, 0);
        acc1 = MFMA16(a1, wregS[kt], acc1, 0, 0, 0);
      }
    }

    // ---- epilogue ----
    char* ringSlot = L ? ((char*)Ring1 + (size_t)(t & ring1mask)*65536)
                       : ((char*)Ring0 + (size_t)t*65536);
    float hyv[2][4];
    float psum = 0.f;
    #pragma unroll
    for (int m = 0; m < 2; ++m){
      f32x4 av = m ? acc1 : acc0;
      #pragma unroll
      for (int r = 0; r < 4; ++r){
        float g  = av[r] + bia + et*rsv;
        float p4 = __shfl_xor(g, 4), p8 = __shfl_xor(g, 8), p12 = __shfl_xor(p4, 8);
        float iv = (q==0)?g:(q==1)?p4:(q==2)?p8:p12;
        float fv = (q==1)?g:(q==0)?p4:(q==3)?p8:p12;
        float gv = (q==2)?g:(q==3)?p4:(q==0)?p8:p12;
        float ov = (q==3)?g:(q==2)?p4:(q==1)?p8:p12;
        iv = fminf(fmaxf(0.2f*iv + 0.5f, 0.f), 1.f);
        fv = fminf(fmaxf(0.2f*fv + 0.5f, 0.f), 1.f);
        gv = fminf(fmaxf(gv, -1.f), 1.f);
        ov = fminf(fmaxf(0.2f*ov + 0.5f, 0.f), 1.f);
        float cc = fv*(creg[m][r] + et) + iv*gv;
        creg[m][r] = cc;
        float hy = ov * fminf(fmaxf(cc, -1.f), 1.f);
        hyv[m][r] = hy;
        if (c < 4) psum += hy;

        unsigned short hu = f2bf(hy);
        unsigned p2 = (unsigned)hu | (((unsigned)__shfl_xor((int)hu, 1)) << 16);
        unsigned q2 = (unsigned)__shfl_xor((int)p2, 2);
        if (c == 0){
          int sub = (lane>>4)*4 + r;
          size_t bo = (size_t)((jc>>5)*2 + m)*1024
                    + (size_t)(sub | (((jc>>3)&3)<<4))*16 + (size_t)(jc&7)*2;
          AGST(reinterpret_cast<u64*>(ringSlot + bo), (u64)p2 | ((u64)q2 << 32));
        }
      }
    }
    if (L == 0){
      #pragma unroll
      for (int mm = 32; mm; mm >>= 1) psum += __shfl_xor(psum, mm);
      if (lane == 0) ldsPs[w] = psum;
    }
    asm volatile("s_waitcnt vmcnt(0)" ::: "memory");   // drain ring publishes
    __syncthreads();
    if (tid == 0){
      if (L == 0){
        float bs = ldsPs[0] + ldsPs[1] + ldsPs[2] + ldsPs[3];
        AGST(reinterpret_cast<unsigned*>(epsP + (size_t)t*64 + bid),
             (unsigned)(int)llrintf(bs*65536.f));
        asm volatile("s_waitcnt vmcnt(0)" ::: "memory");
      }
      asm volatile("global_store_short %0, %1, off sc0 sc1"
                   :: "v"(myFlagA), "v"((unsigned)(t+1)) : "memory");
    }

    // ---- off-critical-path outputs ----
    if (L){
      #pragma unroll
      for (int m = 0; m < 2; ++m)
        #pragma unroll
        for (int r = 0; r < 4; ++r){
          float hy = hyv[m][r];
          float f1 = __shfl_xor(hy, 1), f2 = __shfl_xor(hy, 2), f3 = __shfl_xor(f1, 2);
          if (c == 0){
            int row = m*16 + (lane>>4)*4 + r;
            f32x4 o4 = {hy, f1, f2, f3};
            *reinterpret_cast<f32x4*>(out + (size_t)t*32768 + row*1024 + jc) = o4;
          }
        }
    }
    if (t == T_STEPS-1){
      #pragma unroll
      for (int m = 0; m < 2; ++m)
        #pragma unroll
        for (int r = 0; r < 4; ++r)
          if (c < 4){
            int row = m*16 + (lane>>4)*4 + r;
            outHn[row*1024 + jw] = hyv[m][r];
            outCn[row*1024 + jw] = creg[m][r];
          }
    }
  }
}

// ---------------- host ----------------

extern "C" void kernel_launch(void* const* d_in, const int* in_sizes, int n_in,
                              void* d_out, int out_size, void* d_ws, size_t ws_size,
                              hipStream_t stream)
{
  const float* x    = (const float*)d_in[0];
  const float* h0   = (const float*)d_in[1];
  const float* c0   = (const float*)d_in[2];
  const float* Wih0 = (const float*)d_in[3];
  const float* Whh0 = (const float*)d_in[4];
  const float* bih0 = (const float*)d_in[5];
  const float* bhh0 = (const float*)d_in[6];
  const float* Wih1 = (const float*)d_in[7];
  const float* Whh1 = (const float*)d_in[8];
  const float* bih1 = (const float*)d_in[9];
  const float* bhh1 = (const float*)d_in[10];
  float* out = (float*)d_out;

  char* ws = (char*)d_ws;
  size_t off = 0;
  auto alloc = [&](size_t bytes)->char* {
    char* p = ws + off; off += (bytes + 255) & ~(size_t)255; return p;
  };
  unsigned short* Xf    = (unsigned short*)alloc((size_t)T_STEPS*65536);   // 32MB
  unsigned short* Ring0 = (unsigned short*)alloc((size_t)T_STEPS*65536);   // 32MB
  unsigned short* HiniF = (unsigned short*)alloc(2*65536);
  float* eps0 = (float*)alloc(T_STEPS*4);
  float* bias = (float*)alloc(2*4096*4);
  float* rs   = (float*)alloc(2*4096*4);
  int*   epsP = (int*)alloc((size_t)T_STEPS*64*4);                         // 128KB
  char* sync  = alloc(512);                       // flag0 (128B) + flag1 (128B)
  unsigned short* flag0 = (unsigned short*)sync;
  unsigned short* flag1 = (unsigned short*)(sync + 128);
  // Ring1: prefer 512 unique slots (cached staging); fall back to 8 + bypass.
  size_t remain  = (off <= ws_size) ? (ws_size - off) : 0;
  int r1slots    = (remain >= (size_t)(T_STEPS+1)*65536) ? T_STEPS : 8;
  unsigned short* Ring1 = (unsigned short*)alloc((size_t)r1slots*65536);
  int r1mask   = r1slots - 1;
  int r1cached = (r1slots == T_STEPS) ? 1 : 0;
  if (off > ws_size)
    fprintf(stderr, "HardLSTM: ws too small, need %zu have %zu\n", off, ws_size);

  hipMemsetAsync(sync, 0, 512, stream);
  prep_xfrag<<<8192, 256, 0, stream>>>(x, Xf);
  prep_hfrag<<<32, 256, 0, stream>>>(h0, HiniF);
  reduce_mean_f32<<<T_STEPS, 256, 0, stream>>>(x, eps0, 1.0f);  // mean(x_t)+1
  prep_rs<<<2048, 256, 0, stream>>>(Wih0, Whh0, Wih1, Whh1,
                                    bih0, bhh0, bih1, bhh1, rs, bias);

  rec11<<<128, 256, 0, stream>>>(Xf, HiniF, Ring0, Ring1, r1mask, r1cached, out,
      Wih0, Whh0, Wih1, Whh1, bias, rs, eps0, c0, epsP, flag0, flag1);
}

// Round 12
// 6479.869 us; speedup vs baseline: 1.7152x; 1.0234x over previous
//
#include <hip/hip_runtime.h>
#include <cstdio>

// HardLSTM (2 layers, T=512, B=32, IN=H=1024) on MI355X.
// Round 12: remove ~3 serial LLC round-trips per step; arithmetic untouched.
//  - L1 prefetches L0 products (eps, y0->ldsB) BEFORE its own flag1 spin
//    (L0 free-runs ahead; spin flag0 is instant in steady state).
//  - eps partials published per-wave as raw fp32 bits before the common
//    drain; L1 recombines with the exact r11 expression (bit-identical).
//  - separate ldsA (h) / ldsB (y0) buffers; one less syncthreads.
// Everything else (chain order, staging paths, flags) identical to r11.

#define T_STEPS 512
#define DEADLINE_TICKS 6000000ULL   // ~60ms @ 100MHz

typedef __bf16 bf16x8 __attribute__((ext_vector_type(8)));
typedef float  f32x4  __attribute__((ext_vector_type(4)));
typedef unsigned int u32x4 __attribute__((ext_vector_type(4)));
typedef unsigned long long u64;

#define AGLD(p)   __hip_atomic_load((p), __ATOMIC_RELAXED, __HIP_MEMORY_SCOPE_AGENT)
#define AGST(p,v) __hip_atomic_store((p), (v), __ATOMIC_RELAXED, __HIP_MEMORY_SCOPE_AGENT)
#define MFMA16 __builtin_amdgcn_mfma_f32_16x16x32_bf16

__device__ __forceinline__ u64 rtick(){ return __builtin_amdgcn_s_memrealtime(); }

__device__ __forceinline__ unsigned short f2bf(float f){
  union { float f; unsigned u; } v; v.f = f;
  unsigned r = v.u + 0x7FFFu + ((v.u >> 16) & 1u);   // RNE
  return (unsigned short)(r >> 16);
}
__device__ __forceinline__ bf16x8 packbf(f32x4 a, f32x4 b){
  unsigned u0 = f2bf(a[0]) | ((unsigned)f2bf(a[1])<<16);
  unsigned u1 = f2bf(a[2]) | ((unsigned)f2bf(a[3])<<16);
  unsigned u2 = f2bf(b[0]) | ((unsigned)f2bf(b[1])<<16);
  unsigned u3 = f2bf(b[2]) | ((unsigned)f2bf(b[3])<<16);
  u32x4 cv = {u0,u1,u2,u3};
  return __builtin_bit_cast(bf16x8, cv);
}
// frag-layout byte offset of (row 0..31, k8 = k>>3 in 0..127) in a 64KB A-block
__device__ __forceinline__ int fragOff(int row, int k8){
  return ((k8>>2)*2 + (row>>4))*1024 + ((row&15) | ((k8&3)<<4))*16;
}
__device__ __forceinline__ bf16x8 ld_frag_plain(const char* p){
  u32x4 v = *reinterpret_cast<const u32x4*>(p);
  return __builtin_bit_cast(bf16x8, v);
}
__device__ __forceinline__ bf16x8 lds_frag(const char* p){
  u32x4 v = *reinterpret_cast<const u32x4*>(p);
  return __builtin_bit_cast(bf16x8, v);
}

// Stage 64KB global -> LDS, plain cached loads (L2-shared per XCD).
__device__ __forceinline__ void stage64k_c(const char* src, char* dst, int tid){
  const u32x4* s = reinterpret_cast<const u32x4*>(src) + tid;
  u32x4 r0 = s[0],    r1 = s[256],  r2 = s[512],  r3 = s[768];
  u32x4 r4 = s[1024], r5 = s[1280], r6 = s[1536], r7 = s[1792];
  u32x4 r8 = s[2048], r9 = s[2304], ra = s[2560], rb = s[2816];
  u32x4 rc = s[3072], rd = s[3328], re = s[3584], rf = s[3840];
  u32x4* d = (u32x4*)(dst + tid*16);
  d[0]=r0; d[256]=r1; d[512]=r2; d[768]=r3;
  d[1024]=r4; d[1280]=r5; d[1536]=r6; d[1792]=r7;
  d[2048]=r8; d[2304]=r9; d[2560]=ra; d[2816]=rb;
  d[3072]=rc; d[3328]=rd; d[3584]=re; d[3840]=rf;
}
// Stage 64KB global -> LDS, bypass (sc0 sc1) loads — r8-proven fallback path.
__device__ __forceinline__ void stage64k_b(const char* src, char* dst, int tid){
  u32x4 r0,r1,r2,r3,r4,r5,r6,r7,r8,r9,ra,rb,rc,rd,re,rf;
  u64 a = (u64)(uintptr_t)src + (u64)tid*16;
  #define LD(reg, off) asm volatile("global_load_dwordx4 %0, %1, off sc0 sc1" \
                                    : "=v"(reg) : "v"(a + (off)) : "memory")
  LD(r0,0); LD(r1,4096); LD(r2,8192); LD(r3,12288);
  LD(r4,16384); LD(r5,20480); LD(r6,24576); LD(r7,28672);
  LD(r8,32768); LD(r9,36864); LD(ra,40960); LD(rb,45056);
  LD(rc,49152); LD(rd,53248); LD(re,57344); LD(rf,61440);
  #undef LD
  asm volatile("s_waitcnt vmcnt(0)" ::: "memory");
  u32x4* d = (u32x4*)(dst + tid*16);
  d[0]=r0; d[256]=r1; d[512]=r2; d[768]=r3;
  d[1024]=r4; d[1280]=r5; d[1536]=r6; d[1792]=r7;
  d[2048]=r8; d[2304]=r9; d[2560]=ra; d[2816]=rb;
  d[3072]=rc; d[3328]=rd; d[3584]=re; d[3840]=rf;
}

// Spin until all 64 u16 flags >= tgt. Wave lanes 0..7 each poll 16B (bypass).
__device__ __forceinline__ void spin64(const unsigned short* f, unsigned tgt,
                                       int lane, u64 dl){
  if (lane < 8){
    u64 a = (u64)(uintptr_t)f + (u64)lane*16;
    while (true){
      u32x4 v;
      asm volatile("global_load_dwordx4 %0, %1, off sc0 sc1\n\ts_waitcnt vmcnt(0)"
                   : "=v"(v) : "v"(a) : "memory");
      bool ok = true;
      #pragma unroll
      for (int i=0;i<4;++i){
        unsigned u = v[i];
        ok = ok && ((u & 0xFFFFu) >= tgt) && ((u >> 16) >= tgt);
      }
      if (__all((int)ok)) break;
      if (rtick() > dl) break;
    }
  }
  asm volatile("" ::: "memory");
}

// ---------------- prep kernels ----------------

__global__ void prep_xfrag(const float* __restrict__ x, unsigned short* __restrict__ xf){
  int tid = blockIdx.x*256 + threadIdx.x;      // 2,097,152 total
  int k8 = tid & 127, row = (tid>>7)&31, t = tid>>12;
  const float* s = x + ((size_t)(t*32+row)*1024 + k8*8);
  f32x4 a = *reinterpret_cast<const f32x4*>(s);
  f32x4 b = *reinterpret_cast<const f32x4*>(s+4);
  f32x4 a1 = {a[0]+1.f,a[1]+1.f,a[2]+1.f,a[3]+1.f};
  f32x4 b1 = {b[0]+1.f,b[1]+1.f,b[2]+1.f,b[3]+1.f};
  bf16x8 v = packbf(a1,b1);
  *reinterpret_cast<bf16x8*>((char*)xf + (size_t)t*65536 + fragOff(row,k8)) = v;
}

__global__ void prep_hfrag(const float* __restrict__ h0, unsigned short* __restrict__ hf){
  int tid = blockIdx.x*256 + threadIdx.x;      // 8192 total
  int k8 = tid & 127, row = (tid>>7)&31, L = tid>>12;
  const float* s = h0 + ((size_t)(L*32+row)*1024 + k8*8);
  f32x4 a = *reinterpret_cast<const f32x4*>(s);
  f32x4 b = *reinterpret_cast<const f32x4*>(s+4);
  bf16x8 v = packbf(a,b);
  *reinterpret_cast<bf16x8*>((char*)hf + (size_t)L*65536 + fragOff(row,k8)) = v;
}

__global__ void reduce_mean_f32(const float* __restrict__ src, float* __restrict__ out, float add){
  __shared__ float red[256];
  int t = blockIdx.x, tid = threadIdx.x;
  const float* p = src + (size_t)t*32768;
  float s = 0.f;
  for (int i = tid; i < 32768; i += 256) s += p[i];
  red[tid] = s; __syncthreads();
  for (int o = 128; o > 0; o >>= 1){ if (tid < o) red[tid] += red[tid+o]; __syncthreads(); }
  if (tid == 0) out[t] = red[0]*(1.f/32768.f) + add;
}

__global__ void prep_rs(const float* __restrict__ Wih0, const float* __restrict__ Whh0,
                        const float* __restrict__ Wih1, const float* __restrict__ Whh1,
                        const float* __restrict__ bih0, const float* __restrict__ bhh0,
                        const float* __restrict__ bih1, const float* __restrict__ bhh1,
                        float* __restrict__ rs, float* __restrict__ bias){
  int task = blockIdx.x*4 + (threadIdx.x >> 6);
  int lane = threadIdx.x & 63;
  int L = task >> 12, n = task & 4095;
  const float* pi = (L ? Wih1 : Wih0) + (size_t)n*1024;
  const float* ph = (L ? Whh1 : Whh0) + (size_t)n*1024;
  float s = 0.f;
  #pragma unroll
  for (int e = 0; e < 16; ++e){ int k = lane + e*64; s += pi[k] + ph[k]; }
  #pragma unroll
  for (int m = 32; m; m >>= 1) s += __shfl_xor(s, m);
  if (lane == 0){
    rs[task]   = s;
    bias[task] = (L ? bih1[n] : bih0[n]) + (L ? bhh1[n] : bhh0[n]);
  }
}

// ---------------- recurrent kernel ----------------
// grid 128 x 256. Blocks 0..63: layer 0; 64..127: layer 1 (1 step behind).
// Block bid owns h-cols jb=bid*16 (x4 gates = 64 ncols).
// Wave w=cg handles cols jc=jb+w*4 (x4 gates), rows 0..31 via acc0/acc1.
__global__ __launch_bounds__(256, 1) void rec12(
    const unsigned short* __restrict__ Xf,     // [512][64KB] frag
    const unsigned short* __restrict__ HiniF,  // [2][64KB] frag
    unsigned short* __restrict__ Ring0,        // [512][32768] frag (y0)
    unsigned short* __restrict__ Ring1,        // [r1slots][32768] frag (h1)
    int ring1mask, int ring1cached,
    float* __restrict__ out,
    const float* __restrict__ Wih0, const float* __restrict__ Whh0,
    const float* __restrict__ Wih1, const float* __restrict__ Whh1,
    const float* __restrict__ biasC, const float* __restrict__ rsC,  // [2*4096]
    const float* __restrict__ eps0, const float* __restrict__ c0,
    unsigned* __restrict__ epsP,               // [512][256] raw f32 bits (4/block)
    unsigned short* __restrict__ flag0,        // 64 u16 (128B)
    unsigned short* __restrict__ flag1)
{
  __shared__ char ldsA[65536];                 // h-tile
  __shared__ char ldsB[65536];                 // y0-tile (L1 only)

  const int tid  = threadIdx.x;
  const int lane = tid & 63;
  const int w    = tid >> 6;                   // = cg, 0..3
  const int L    = blockIdx.x >> 6;
  const int bid  = blockIdx.x & 63;
  const int jb   = bid * 16;
  const int jc   = jb + w*4;
  const int c    = lane & 15;
  const int q    = c >> 2;
  const int ncol = q*1024 + jc + (c & 3);
  const int koff = (lane >> 4) << 3;
  const u64 dl   = rtick() + DEADLINE_TICKS;

  // ONE prologue fence (drop stale clean lines from previous replay).
  __builtin_amdgcn_fence(__ATOMIC_ACQUIRE, "agent");
  __syncthreads();

  // chain order per r8: L0 = x-then-h, L1 = h-then-y0.
  const float* Wfirst = L ? Whh1 : Wih0;
  const float* Wsec   = L ? Wih1 : Whh0;

  // ---- full W slice into VGPRs (rule #20: all consumer loops fully unrolled) ----
  bf16x8 wregF[32], wregS[32];
  {
    const float* sF = Wfirst + (size_t)ncol*1024 + koff;
    const float* sS = Wsec   + (size_t)ncol*1024 + koff;
    #pragma unroll
    for (int kt = 0; kt < 32; ++kt){
      f32x4 a = *reinterpret_cast<const f32x4*>(sF + kt*32);
      f32x4 b = *reinterpret_cast<const f32x4*>(sF + kt*32 + 4);
      wregF[kt] = packbf(a, b);
      f32x4 cc = *reinterpret_cast<const f32x4*>(sS + kt*32);
      f32x4 d  = *reinterpret_cast<const f32x4*>(sS + kt*32 + 4);
      wregS[kt] = packbf(cc, d);
    }
  }

  const float bia = biasC[L*4096 + ncol];
  const float rsv = rsC[L*4096 + ncol];
  const int jw = jc + (c & 3);
  float creg[2][4];
  #pragma unroll
  for (int m = 0; m < 2; ++m)
    #pragma unroll
    for (int r = 0; r < 4; ++r)
      creg[m][r] = c0[L*32768 + (m*16 + (lane>>4)*4 + r)*1024 + jw];

  float* outHn = out + 16777216 + L*32768;
  float* outCn = out + 16777216 + 65536 + L*32768;
  const u64 myFlagA = (u64)(uintptr_t)((L ? flag1 : flag0) + bid);

  for (int t = 0; t < T_STEPS; ++t){
    f32x4 acc0 = {0.f,0.f,0.f,0.f}, acc1 = {0.f,0.f,0.f,0.f};
    float et;

    if (L == 0){
      // x-half FIRST (chain start) — independent of h, hides the spin
      const char* Ax = (const char*)Xf + (size_t)t*65536;
      #pragma unroll
      for (int kt = 0; kt < 32; ++kt){
        bf16x8 a0 = ld_frag_plain(Ax + (kt*2 + 0)*1024 + lane*16);
        bf16x8 a1 = ld_frag_plain(Ax + (kt*2 + 1)*1024 + lane*16);
        acc0 = MFMA16(a0, wregF[kt], acc0, 0, 0, 0);
        acc1 = MFMA16(a1, wregF[kt], acc1, 0, 0, 0);
      }
      et = eps0[t];
      if (w == 0 && t > 0) spin64(flag0, (unsigned)t, lane, dl);
      __syncthreads();
      const char* hsrc = (t == 0) ? (const char*)HiniF
                                  : (const char*)Ring0 + (size_t)(t-1)*65536;
      stage64k_c(hsrc, ldsA, tid);               // cached: once per XCD
      __syncthreads();
      #pragma unroll
      for (int kt = 0; kt < 32; ++kt){
        bf16x8 a0 = lds_frag(ldsA + (kt*2 + 0)*1024 + lane*16);
        bf16x8 a1 = lds_frag(ldsA + (kt*2 + 1)*1024 + lane*16);
        acc0 = MFMA16(a0, wregS[kt], acc0, 0, 0, 0);
        acc1 = MFMA16(a1, wregS[kt], acc1, 0, 0, 0);
      }
    } else {
      // ---- prefetch L0 products FIRST (L0 runs ahead; near-instant) ----
      if (w == 0) spin64(flag0, (unsigned)(t+1), lane, dl);
      __syncthreads();
      // eps1[t]: recombine per-block exactly as r11's tid0 did
      {
        const u64* ep = reinterpret_cast<const u64*>(epsP + (size_t)t*256) + lane*2;
        u64 v01 = AGLD(ep), v23 = AGLD(ep + 1);
        union { unsigned u; float f; } w0x,w1x,w2x,w3x;
        w0x.u = (unsigned)v01; w1x.u = (unsigned)(v01>>32);
        w2x.u = (unsigned)v23; w3x.u = (unsigned)(v23>>32);
        float bs = ((w0x.f + w1x.f) + w2x.f) + w3x.f;
        int s = (int)llrintf(bs * 65536.f);
        #pragma unroll
        for (int mm = 32; mm; mm >>= 1) s += __shfl_xor(s, mm);
        et = (float)s * 4.6566128730773926e-10f;   // / (2^16 * 32768)
      }
      stage64k_c((const char*)Ring0 + (size_t)t*65536, ldsB, tid);  // y0[t]
      // ---- own-layer h (the real dependency) ----
      if (w == 0 && t > 0) spin64(flag1, (unsigned)t, lane, dl);
      __syncthreads();                           // covers ldsB writes + flag1
      const char* hsrc = (t == 0) ? (const char*)HiniF + 65536
                                  : (const char*)Ring1 + (size_t)((t-1) & ring1mask)*65536;
      if (t == 0 || ring1cached) stage64k_c(hsrc, ldsA, tid);
      else                       stage64k_b(hsrc, ldsA, tid);
      __syncthreads();
      // h-chain then y0-chain: SAME acc sequence as r11 (bit-exact)
      #pragma unroll
      for (int kt = 0; kt < 32; ++kt){
        bf16x8 a0 = lds_frag(ldsA + (kt*2 + 0)*1024 + lane*16);
        bf16x8 a1 = lds_frag(ldsA + (kt*2 + 1)*1024 + lane*16);
        acc0 = MFMA16(a0, wregF[kt], acc0, 0, 0, 0);
        acc1 = MFMA16(a1, wregF[kt], acc1, 0, 0, 0);
      }
      #pragma unroll
      for (int kt = 0; kt < 32; ++kt){
        bf16x8 a0 = lds_frag(ldsB + (kt*2 + 0)*1024 + lane*16);
        bf16x8 a1 = lds_frag(ldsB + (kt*2 + 1)*1024 + lane*16);
        acc0 = MFMA16(a0, wregS[kt], acc0, 0, 0, 0);
        acc1 = MFMA16(a1, wregS[kt], acc1, 0, 0, 0);
      }
    }

    // ---- epilogue ----
    char* ringSlot = L ? ((char*)Ring1 + (size_t)(t & ring1mask)*65536)
                       : ((char*)Ring0 + (size_t)t*65536);
    float hyv[2][4];
    float psum = 0.f;
    #pragma unroll
    for (int m = 0; m < 2; ++m){
      f32x4 av = m ? acc1 : acc0;
      #pragma unroll
      for (int r = 0; r < 4; ++r){
        float g  = av[r] + bia + et*rsv;
        float p4 = __shfl_xor(g, 4), p8 = __shfl_xor(g, 8), p12 = __shfl_xor(p4, 8);
        float iv = (q==0)?g:(q==1)?p4:(q==2)?p8:p12;
        float fv = (q==1)?g:(q==0)?p4:(q==3)?p8:p12;
        float gv = (q==2)?g:(q==3)?p4:(q==0)?p8:p12;
        float ov = (q==3)?g:(q==2)?p4:(q==1)?p8:p12;
        iv = fminf(fmaxf(0.2f*iv + 0.5f, 0.f), 1.f);
        fv = fminf(fmaxf(0.2f*fv + 0.5f, 0.f), 1.f);
        gv = fminf(fmaxf(gv, -1.f), 1.f);
        ov = fminf(fmaxf(0.2f*ov + 0.5f, 0.f), 1.f);
        float cc = fv*(creg[m][r] + et) + iv*gv;
        creg[m][r] = cc;
        float hy = ov * fminf(fmaxf(cc, -1.f), 1.f);
        hyv[m][r] = hy;
        if (c < 4) psum += hy;

        unsigned short hu = f2bf(hy);
        unsigned p2 = (unsigned)hu | (((unsigned)__shfl_xor((int)hu, 1)) << 16);
        unsigned q2 = (unsigned)__shfl_xor((int)p2, 2);
        if (c == 0){
          int sub = (lane>>4)*4 + r;
          size_t bo = (size_t)((jc>>5)*2 + m)*1024
                    + (size_t)(sub | (((jc>>3)&3)<<4))*16 + (size_t)(jc&7)*2;
          AGST(reinterpret_cast<u64*>(ringSlot + bo), (u64)p2 | ((u64)q2 << 32));
        }
      }
    }
    if (L == 0){
      // per-wave raw psum published before the common drain (1 store/wave)
      #pragma unroll
      for (int mm = 32; mm; mm >>= 1) psum += __shfl_xor(psum, mm);
      if (lane == 0){
        union { float f; unsigned u; } pb; pb.f = psum;
        AGST(epsP + (size_t)t*256 + (bid<<2) + w, pb.u);
      }
    }
    asm volatile("s_waitcnt vmcnt(0)" ::: "memory");   // per-wave drain (ring+eps)
    __syncthreads();
    if (tid == 0)
      asm volatile("global_store_short %0, %1, off sc0 sc1"
                   :: "v"(myFlagA), "v"((unsigned)(t+1)) : "memory");

    // ---- off-critical-path outputs ----
    if (L){
      #pragma unroll
      for (int m = 0; m < 2; ++m)
        #pragma unroll
        for (int r = 0; r < 4; ++r){
          float hy = hyv[m][r];
          float f1 = __shfl_xor(hy, 1), f2 = __shfl_xor(hy, 2), f3 = __shfl_xor(f1, 2);
          if (c == 0){
            int row = m*16 + (lane>>4)*4 + r;
            f32x4 o4 = {hy, f1, f2, f3};
            *reinterpret_cast<f32x4*>(out + (size_t)t*32768 + row*1024 + jc) = o4;
          }
        }
    }
    if (t == T_STEPS-1){
      #pragma unroll
      for (int m = 0; m < 2; ++m)
        #pragma unroll
        for (int r = 0; r < 4; ++r)
          if (c < 4){
            int row = m*16 + (lane>>4)*4 + r;
            outHn[row*1024 + jw] = hyv[m][r];
            outCn[row*1024 + jw] = creg[m][r];
          }
    }
  }
}

// ---------------- host ----------------

extern "C" void kernel_launch(void* const* d_in, const int* in_sizes, int n_in,
                              void* d_out, int out_size, void* d_ws, size_t ws_size,
                              hipStream_t stream)
{
  const float* x    = (const float*)d_in[0];
  const float* h0   = (const float*)d_in[1];
  const float* c0   = (const float*)d_in[2];
  const float* Wih0 = (const float*)d_in[3];
  const float* Whh0 = (const float*)d_in[4];
  const float* bih0 = (const float*)d_in[5];
  const float* bhh0 = (const float*)d_in[6];
  const float* Wih1 = (const float*)d_in[7];
  const float* Whh1 = (const float*)d_in[8];
  const float* bih1 = (const float*)d_in[9];
  const float* bhh1 = (const float*)d_in[10];
  float* out = (float*)d_out;

  char* ws = (char*)d_ws;
  size_t off = 0;
  auto alloc = [&](size_t bytes)->char* {
    char* p = ws + off; off += (bytes + 255) & ~(size_t)255; return p;
  };
  unsigned short* Xf    = (unsigned short*)alloc((size_t)T_STEPS*65536);   // 32MB
  unsigned short* Ring0 = (unsigned short*)alloc((size_t)T_STEPS*65536);   // 32MB
  unsigned short* HiniF = (unsigned short*)alloc(2*65536);
  float* eps0 = (float*)alloc(T_STEPS*4);
  float* bias = (float*)alloc(2*4096*4);
  float* rs   = (float*)alloc(2*4096*4);
  unsigned* epsP = (unsigned*)alloc((size_t)T_STEPS*256*4);                // 512KB
  char* sync  = alloc(512);                       // flag0 (128B) + flag1 (128B)
  unsigned short* flag0 = (unsigned short*)sync;
  unsigned short* flag1 = (unsigned short*)(sync + 128);
  // Ring1: prefer 512 unique slots (cached staging); fall back to 8 + bypass.
  size_t remain  = (off <= ws_size) ? (ws_size - off) : 0;
  int r1slots    = (remain >= (size_t)(T_STEPS+1)*65536) ? T_STEPS : 8;
  unsigned short* Ring1 = (unsigned short*)alloc((size_t)r1slots*65536);
  int r1mask   = r1slots - 1;
  int r1cached = (r1slots == T_STEPS) ? 1 : 0;
  if (off > ws_size)
    fprintf(stderr, "HardLSTM: ws too small, need %zu have %zu\n", off, ws_size);

  hipMemsetAsync(sync, 0, 512, stream);
  prep_xfrag<<<8192, 256, 0, stream>>>(x, Xf);
  prep_hfrag<<<32, 256, 0, stream>>>(h0, HiniF);
  reduce_mean_f32<<<T_STEPS, 256, 0, stream>>>(x, eps0, 1.0f);  // mean(x_t)+1
  prep_rs<<<2048, 256, 0, stream>>>(Wih0, Whh0, Wih1, Whh1,
                                    bih0, bhh0, bih1, bhh1, rs, bias);

  rec12<<<128, 256, 0, stream>>>(Xf, HiniF, Ring0, Ring1, r1mask, r1cached, out,
      Wih0, Whh0, Wih1, Whh1, bias, rs, eps0, c0, epsP, flag0, flag1);
}

// Round 13
// 6274.927 us; speedup vs baseline: 1.7712x; 1.0327x over previous
//
#include <hip/hip_runtime.h>
#include <cstdio>

// HardLSTM (2 layers, T=512, B=32, IN=H=1024) on MI355X.
// Round 13: barrier de-convoying + async stage split. Arithmetic untouched.
//  - Flags spread to ONE u32 per 128B line (r8 packed 64 flags into 2 lines,
//    recreating the r2 hot-line convoy; r3's lesson re-applied). Publish =
//    1 sc0sc1 dword store to a private line; spin = 64 lanes poll 64 lines.
//  - L1's y0-tile staged via register prefetch issued right after flag0
//    clears; the flag1 spin absorbs the LLC latency; LDS write after sync
//    (T14 split). L1's serial stage cost leaves the critical path.
// Everything else identical to r12 (bit-exact absmax-4.0 chain).

#define T_STEPS 512
#define DEADLINE_TICKS 6000000ULL   // ~60ms @ 100MHz

typedef __bf16 bf16x8 __attribute__((ext_vector_type(8)));
typedef float  f32x4  __attribute__((ext_vector_type(4)));
typedef unsigned int u32x4 __attribute__((ext_vector_type(4)));
typedef unsigned long long u64;

#define AGLD(p)   __hip_atomic_load((p), __ATOMIC_RELAXED, __HIP_MEMORY_SCOPE_AGENT)
#define AGST(p,v) __hip_atomic_store((p), (v), __ATOMIC_RELAXED, __HIP_MEMORY_SCOPE_AGENT)
#define MFMA16 __builtin_amdgcn_mfma_f32_16x16x32_bf16

__device__ __forceinline__ u64 rtick(){ return __builtin_amdgcn_s_memrealtime(); }

__device__ __forceinline__ unsigned short f2bf(float f){
  union { float f; unsigned u; } v; v.f = f;
  unsigned r = v.u + 0x7FFFu + ((v.u >> 16) & 1u);   // RNE
  return (unsigned short)(r >> 16);
}
__device__ __forceinline__ bf16x8 packbf(f32x4 a, f32x4 b){
  unsigned u0 = f2bf(a[0]) | ((unsigned)f2bf(a[1])<<16);
  unsigned u1 = f2bf(a[2]) | ((unsigned)f2bf(a[3])<<16);
  unsigned u2 = f2bf(b[0]) | ((unsigned)f2bf(b[1])<<16);
  unsigned u3 = f2bf(b[2]) | ((unsigned)f2bf(b[3])<<16);
  u32x4 cv = {u0,u1,u2,u3};
  return __builtin_bit_cast(bf16x8, cv);
}
// frag-layout byte offset of (row 0..31, k8 = k>>3 in 0..127) in a 64KB A-block
__device__ __forceinline__ int fragOff(int row, int k8){
  return ((k8>>2)*2 + (row>>4))*1024 + ((row&15) | ((k8&3)<<4))*16;
}
__device__ __forceinline__ bf16x8 ld_frag_plain(const char* p){
  u32x4 v = *reinterpret_cast<const u32x4*>(p);
  return __builtin_bit_cast(bf16x8, v);
}
__device__ __forceinline__ bf16x8 lds_frag(const char* p){
  u32x4 v = *reinterpret_cast<const u32x4*>(p);
  return __builtin_bit_cast(bf16x8, v);
}

// Stage 64KB global -> LDS, plain cached loads (L2-shared per XCD).
__device__ __forceinline__ void stage64k_c(const char* src, char* dst, int tid){
  const u32x4* s = reinterpret_cast<const u32x4*>(src) + tid;
  u32x4 r0 = s[0],    r1 = s[256],  r2 = s[512],  r3 = s[768];
  u32x4 r4 = s[1024], r5 = s[1280], r6 = s[1536], r7 = s[1792];
  u32x4 r8 = s[2048], r9 = s[2304], ra = s[2560], rb = s[2816];
  u32x4 rc = s[3072], rd = s[3328], re = s[3584], rf = s[3840];
  u32x4* d = (u32x4*)(dst + tid*16);
  d[0]=r0; d[256]=r1; d[512]=r2; d[768]=r3;
  d[1024]=r4; d[1280]=r5; d[1536]=r6; d[1792]=r7;
  d[2048]=r8; d[2304]=r9; d[2560]=ra; d[2816]=rb;
  d[3072]=rc; d[3328]=rd; d[3584]=re; d[3840]=rf;
}
// Stage 64KB global -> LDS, bypass (sc0 sc1) loads — r8-proven fallback path.
__device__ __forceinline__ void stage64k_b(const char* src, char* dst, int tid){
  u32x4 r0,r1,r2,r3,r4,r5,r6,r7,r8,r9,ra,rb,rc,rd,re,rf;
  u64 a = (u64)(uintptr_t)src + (u64)tid*16;
  #define LD(reg, off) asm volatile("global_load_dwordx4 %0, %1, off sc0 sc1" \
                                    : "=v"(reg) : "v"(a + (off)) : "memory")
  LD(r0,0); LD(r1,4096); LD(r2,8192); LD(r3,12288);
  LD(r4,16384); LD(r5,20480); LD(r6,24576); LD(r7,28672);
  LD(r8,32768); LD(r9,36864); LD(ra,40960); LD(rb,45056);
  LD(rc,49152); LD(rd,53248); LD(re,57344); LD(rf,61440);
  #undef LD
  asm volatile("s_waitcnt vmcnt(0)" ::: "memory");
  u32x4* d = (u32x4*)(dst + tid*16);
  d[0]=r0; d[256]=r1; d[512]=r2; d[768]=r3;
  d[1024]=r4; d[1280]=r5; d[1536]=r6; d[1792]=r7;
  d[2048]=r8; d[2304]=r9; d[2560]=ra; d[2816]=rb;
  d[3072]=rc; d[3328]=rd; d[3584]=re; d[3840]=rf;
}

// Spin until all 64 per-block flags (one u32 per 128B line) >= tgt.
// All 64 lanes poll one line each -> no hot line (r3 lesson, re-applied).
__device__ __forceinline__ void spin64s(const unsigned* f, unsigned tgt,
                                        int lane, u64 dl){
  u64 a = (u64)(uintptr_t)(f + (size_t)lane*32);
  while (true){
    unsigned v;
    asm volatile("global_load_dword %0, %1, off sc0 sc1\n\ts_waitcnt vmcnt(0)"
                 : "=v"(v) : "v"(a) : "memory");
    if (__all((int)(v >= tgt))) break;
    if (rtick() > dl) break;
  }
  asm volatile("" ::: "memory");
}

// ---------------- prep kernels ----------------

__global__ void prep_xfrag(const float* __restrict__ x, unsigned short* __restrict__ xf){
  int tid = blockIdx.x*256 + threadIdx.x;      // 2,097,152 total
  int k8 = tid & 127, row = (tid>>7)&31, t = tid>>12;
  const float* s = x + ((size_t)(t*32+row)*1024 + k8*8);
  f32x4 a = *reinterpret_cast<const f32x4*>(s);
  f32x4 b = *reinterpret_cast<const f32x4*>(s+4);
  f32x4 a1 = {a[0]+1.f,a[1]+1.f,a[2]+1.f,a[3]+1.f};
  f32x4 b1 = {b[0]+1.f,b[1]+1.f,b[2]+1.f,b[3]+1.f};
  bf16x8 v = packbf(a1,b1);
  *reinterpret_cast<bf16x8*>((char*)xf + (size_t)t*65536 + fragOff(row,k8)) = v;
}

__global__ void prep_hfrag(const float* __restrict__ h0, unsigned short* __restrict__ hf){
  int tid = blockIdx.x*256 + threadIdx.x;      // 8192 total
  int k8 = tid & 127, row = (tid>>7)&31, L = tid>>12;
  const float* s = h0 + ((size_t)(L*32+row)*1024 + k8*8);
  f32x4 a = *reinterpret_cast<const f32x4*>(s);
  f32x4 b = *reinterpret_cast<const f32x4*>(s+4);
  bf16x8 v = packbf(a,b);
  *reinterpret_cast<bf16x8*>((char*)hf + (size_t)L*65536 + fragOff(row,k8)) = v;
}

__global__ void reduce_mean_f32(const float* __restrict__ src, float* __restrict__ out, float add){
  __shared__ float red[256];
  int t = blockIdx.x, tid = threadIdx.x;
  const float* p = src + (size_t)t*32768;
  float s = 0.f;
  for (int i = tid; i < 32768; i += 256) s += p[i];
  red[tid] = s; __syncthreads();
  for (int o = 128; o > 0; o >>= 1){ if (tid < o) red[tid] += red[tid+o]; __syncthreads(); }
  if (tid == 0) out[t] = red[0]*(1.f/32768.f) + add;
}

__global__ void prep_rs(const float* __restrict__ Wih0, const float* __restrict__ Whh0,
                        const float* __restrict__ Wih1, const float* __restrict__ Whh1,
                        const float* __restrict__ bih0, const float* __restrict__ bhh0,
                        const float* __restrict__ bih1, const float* __restrict__ bhh1,
                        float* __restrict__ rs, float* __restrict__ bias){
  int task = blockIdx.x*4 + (threadIdx.x >> 6);
  int lane = threadIdx.x & 63;
  int L = task >> 12, n = task & 4095;
  const float* pi = (L ? Wih1 : Wih0) + (size_t)n*1024;
  const float* ph = (L ? Whh1 : Whh0) + (size_t)n*1024;
  float s = 0.f;
  #pragma unroll
  for (int e = 0; e < 16; ++e){ int k = lane + e*64; s += pi[k] + ph[k]; }
  #pragma unroll
  for (int m = 32; m; m >>= 1) s += __shfl_xor(s, m);
  if (lane == 0){
    rs[task]   = s;
    bias[task] = (L ? bih1[n] : bih0[n]) + (L ? bhh1[n] : bhh0[n]);
  }
}

// ---------------- recurrent kernel ----------------
// grid 128 x 256. Blocks 0..63: layer 0; 64..127: layer 1 (1 step behind).
// Block bid owns h-cols jb=bid*16 (x4 gates = 64 ncols).
// Wave w=cg handles cols jc=jb+w*4 (x4 gates), rows 0..31 via acc0/acc1.
__global__ __launch_bounds__(256, 1) void rec13(
    const unsigned short* __restrict__ Xf,     // [512][64KB] frag
    const unsigned short* __restrict__ HiniF,  // [2][64KB] frag
    unsigned short* __restrict__ Ring0,        // [512][32768] frag (y0)
    unsigned short* __restrict__ Ring1,        // [r1slots][32768] frag (h1)
    int ring1mask, int ring1cached,
    float* __restrict__ out,
    const float* __restrict__ Wih0, const float* __restrict__ Whh0,
    const float* __restrict__ Wih1, const float* __restrict__ Whh1,
    const float* __restrict__ biasC, const float* __restrict__ rsC,  // [2*4096]
    const float* __restrict__ eps0, const float* __restrict__ c0,
    unsigned* __restrict__ epsP,               // [512][256] raw f32 bits (4/block)
    unsigned* __restrict__ flag0,              // 64 lines x 128B, u32 at +0
    unsigned* __restrict__ flag1)
{
  __shared__ char ldsA[65536];                 // h-tile
  __shared__ char ldsB[65536];                 // y0-tile (L1 only)

  const int tid  = threadIdx.x;
  const int lane = tid & 63;
  const int w    = tid >> 6;                   // = cg, 0..3
  const int L    = blockIdx.x >> 6;
  const int bid  = blockIdx.x & 63;
  const int jb   = bid * 16;
  const int jc   = jb + w*4;
  const int c    = lane & 15;
  const int q    = c >> 2;
  const int ncol = q*1024 + jc + (c & 3);
  const int koff = (lane >> 4) << 3;
  const u64 dl   = rtick() + DEADLINE_TICKS;

  // ONE prologue fence (drop stale clean lines from previous replay).
  __builtin_amdgcn_fence(__ATOMIC_ACQUIRE, "agent");
  __syncthreads();

  // chain order per r8: L0 = x-then-h, L1 = h-then-y0.
  const float* Wfirst = L ? Whh1 : Wih0;
  const float* Wsec   = L ? Wih1 : Whh0;

  // ---- full W slice into VGPRs (rule #20: all consumer loops fully unrolled) ----
  bf16x8 wregF[32], wregS[32];
  {
    const float* sF = Wfirst + (size_t)ncol*1024 + koff;
    const float* sS = Wsec   + (size_t)ncol*1024 + koff;
    #pragma unroll
    for (int kt = 0; kt < 32; ++kt){
      f32x4 a = *reinterpret_cast<const f32x4*>(sF + kt*32);
      f32x4 b = *reinterpret_cast<const f32x4*>(sF + kt*32 + 4);
      wregF[kt] = packbf(a, b);
      f32x4 cc = *reinterpret_cast<const f32x4*>(sS + kt*32);
      f32x4 d  = *reinterpret_cast<const f32x4*>(sS + kt*32 + 4);
      wregS[kt] = packbf(cc, d);
    }
  }

  const float bia = biasC[L*4096 + ncol];
  const float rsv = rsC[L*4096 + ncol];
  const int jw = jc + (c & 3);
  float creg[2][4];
  #pragma unroll
  for (int m = 0; m < 2; ++m)
    #pragma unroll
    for (int r = 0; r < 4; ++r)
      creg[m][r] = c0[L*32768 + (m*16 + (lane>>4)*4 + r)*1024 + jw];

  float* outHn = out + 16777216 + L*32768;
  float* outCn = out + 16777216 + 65536 + L*32768;
  const u64 myFlagA = (u64)(uintptr_t)((L ? flag1 : flag0) + (size_t)bid*32);

  for (int t = 0; t < T_STEPS; ++t){
    f32x4 acc0 = {0.f,0.f,0.f,0.f}, acc1 = {0.f,0.f,0.f,0.f};
    float et;

    if (L == 0){
      // x-half FIRST (chain start) — independent of h, hides the spin
      const char* Ax = (const char*)Xf + (size_t)t*65536;
      #pragma unroll
      for (int kt = 0; kt < 32; ++kt){
        bf16x8 a0 = ld_frag_plain(Ax + (kt*2 + 0)*1024 + lane*16);
        bf16x8 a1 = ld_frag_plain(Ax + (kt*2 + 1)*1024 + lane*16);
        acc0 = MFMA16(a0, wregF[kt], acc0, 0, 0, 0);
        acc1 = MFMA16(a1, wregF[kt], acc1, 0, 0, 0);
      }
      et = eps0[t];
      if (w == 0 && t > 0) spin64s(flag0, (unsigned)t, lane, dl);
      __syncthreads();
      const char* hsrc = (t == 0) ? (const char*)HiniF
                                  : (const char*)Ring0 + (size_t)(t-1)*65536;
      stage64k_c(hsrc, ldsA, tid);               // cached: once per XCD
      __syncthreads();
      #pragma unroll
      for (int kt = 0; kt < 32; ++kt){
        bf16x8 a0 = lds_frag(ldsA + (kt*2 + 0)*1024 + lane*16);
        bf16x8 a1 = lds_frag(ldsA + (kt*2 + 1)*1024 + lane*16);
        acc0 = MFMA16(a0, wregS[kt], acc0, 0, 0, 0);
        acc1 = MFMA16(a1, wregS[kt], acc1, 0, 0, 0);
      }
    } else {
      // ---- prefetch L0 products FIRST (L0 runs ahead; near-instant) ----
      if (w == 0) spin64s(flag0, (unsigned)(t+1), lane, dl);
      __syncthreads();
      // T14 split: ISSUE y0 loads into registers now; the flag1 spin below
      // absorbs their LLC latency; LDS write happens after the sync.
      const u32x4* sB = reinterpret_cast<const u32x4*>(
                          (const char*)Ring0 + (size_t)t*65536) + tid;
      u32x4 b0 = sB[0],    b1 = sB[256],  b2 = sB[512],  b3 = sB[768];
      u32x4 b4 = sB[1024], b5 = sB[1280], b6 = sB[1536], b7 = sB[1792];
      u32x4 b8 = sB[2048], b9 = sB[2304], ba = sB[2560], bb = sB[2816];
      u32x4 bc = sB[3072], bd = sB[3328], be = sB[3584], bf = sB[3840];
      // eps1[t]: recombine per-block exactly as r11's tid0 did
      {
        const u64* ep = reinterpret_cast<const u64*>(epsP + (size_t)t*256) + lane*2;
        u64 v01 = AGLD(ep), v23 = AGLD(ep + 1);
        union { unsigned u; float f; } w0x,w1x,w2x,w3x;
        w0x.u = (unsigned)v01; w1x.u = (unsigned)(v01>>32);
        w2x.u = (unsigned)v23; w3x.u = (unsigned)(v23>>32);
        float bs = ((w0x.f + w1x.f) + w2x.f) + w3x.f;
        int s = (int)llrintf(bs * 65536.f);
        #pragma unroll
        for (int mm = 32; mm; mm >>= 1) s += __shfl_xor(s, mm);
        et = (float)s * 4.6566128730773926e-10f;   // / (2^16 * 32768)
      }
      // ---- own-layer h (the real dependency) ----
      if (w == 0 && t > 0) spin64s(flag1, (unsigned)t, lane, dl);
      __syncthreads();
      {  // write prefetched y0 tile to ldsB (registers -> LDS, no latency)
        u32x4* d = (u32x4*)(ldsB + tid*16);
        d[0]=b0; d[256]=b1; d[512]=b2; d[768]=b3;
        d[1024]=b4; d[1280]=b5; d[1536]=b6; d[1792]=b7;
        d[2048]=b8; d[2304]=b9; d[2560]=ba; d[2816]=bb;
        d[3072]=bc; d[3328]=bd; d[3584]=be; d[3840]=bf;
      }
      const char* hsrc = (t == 0) ? (const char*)HiniF + 65536
                                  : (const char*)Ring1 + (size_t)((t-1) & ring1mask)*65536;
      if (t == 0 || ring1cached) stage64k_c(hsrc, ldsA, tid);
      else                       stage64k_b(hsrc, ldsA, tid);
      __syncthreads();
      // h-chain then y0-chain: SAME acc sequence as r11 (bit-exact)
      #pragma unroll
      for (int kt = 0; kt < 32; ++kt){
        bf16x8 a0 = lds_frag(ldsA + (kt*2 + 0)*1024 + lane*16);
        bf16x8 a1 = lds_frag(ldsA + (kt*2 + 1)*1024 + lane*16);
        acc0 = MFMA16(a0, wregF[kt], acc0, 0, 0, 0);
        acc1 = MFMA16(a1, wregF[kt], acc1, 0, 0, 0);
      }
      #pragma unroll
      for (int kt = 0; kt < 32; ++kt){
        bf16x8 a0 = lds_frag(ldsB + (kt*2 + 0)*1024 + lane*16);
        bf16x8 a1 = lds_frag(ldsB + (kt*2 + 1)*1024 + lane*16);
        acc0 = MFMA16(a0, wregS[kt], acc0, 0, 0, 0);
        acc1 = MFMA16(a1, wregS[kt], acc1, 0, 0, 0);
      }
    }

    // ---- epilogue ----
    char* ringSlot = L ? ((char*)Ring1 + (size_t)(t & ring1mask)*65536)
                       : ((char*)Ring0 + (size_t)t*65536);
    float hyv[2][4];
    float psum = 0.f;
    #pragma unroll
    for (int m = 0; m < 2; ++m){
      f32x4 av = m ? acc1 : acc0;
      #pragma unroll
      for (int r = 0; r < 4; ++r){
        float g  = av[r] + bia + et*rsv;
        float p4 = __shfl_xor(g, 4), p8 = __shfl_xor(g, 8), p12 = __shfl_xor(p4, 8);
        float iv = (q==0)?g:(q==1)?p4:(q==2)?p8:p12;
        float fv = (q==1)?g:(q==0)?p4:(q==3)?p8:p12;
        float gv = (q==2)?g:(q==3)?p4:(q==0)?p8:p12;
        float ov = (q==3)?g:(q==2)?p4:(q==1)?p8:p12;
        iv = fminf(fmaxf(0.2f*iv + 0.5f, 0.f), 1.f);
        fv = fminf(fmaxf(0.2f*fv + 0.5f, 0.f), 1.f);
        gv = fminf(fmaxf(gv, -1.f), 1.f);
        ov = fminf(fmaxf(0.2f*ov + 0.5f, 0.f), 1.f);
        float cc = fv*(creg[m][r] + et) + iv*gv;
        creg[m][r] = cc;
        float hy = ov * fminf(fmaxf(cc, -1.f), 1.f);
        hyv[m][r] = hy;
        if (c < 4) psum += hy;

        unsigned short hu = f2bf(hy);
        unsigned p2 = (unsigned)hu | (((unsigned)__shfl_xor((int)hu, 1)) << 16);
        unsigned q2 = (unsigned)__shfl_xor((int)p2, 2);
        if (c == 0){
          int sub = (lane>>4)*4 + r;
          size_t bo = (size_t)((jc>>5)*2 + m)*1024
                    + (size_t)(sub | (((jc>>3)&3)<<4))*16 + (size_t)(jc&7)*2;
          AGST(reinterpret_cast<u64*>(ringSlot + bo), (u64)p2 | ((u64)q2 << 32));
        }
      }
    }
    if (L == 0){
      // per-wave raw psum published before the common drain (1 store/wave)
      #pragma unroll
      for (int mm = 32; mm; mm >>= 1) psum += __shfl_xor(psum, mm);
      if (lane == 0){
        union { float f; unsigned u; } pb; pb.f = psum;
        AGST(epsP + (size_t)t*256 + (bid<<2) + w, pb.u);
      }
    }
    asm volatile("s_waitcnt vmcnt(0)" ::: "memory");   // per-wave drain (ring+eps)
    __syncthreads();
    if (tid == 0)
      asm volatile("global_store_dword %0, %1, off sc0 sc1"
                   :: "v"(myFlagA), "v"((unsigned)(t+1)) : "memory");

    // ---- off-critical-path outputs ----
    if (L){
      #pragma unroll
      for (int m = 0; m < 2; ++m)
        #pragma unroll
        for (int r = 0; r < 4; ++r){
          float hy = hyv[m][r];
          float f1 = __shfl_xor(hy, 1), f2 = __shfl_xor(hy, 2), f3 = __shfl_xor(f1, 2);
          if (c == 0){
            int row = m*16 + (lane>>4)*4 + r;
            f32x4 o4 = {hy, f1, f2, f3};
            *reinterpret_cast<f32x4*>(out + (size_t)t*32768 + row*1024 + jc) = o4;
          }
        }
    }
    if (t == T_STEPS-1){
      #pragma unroll
      for (int m = 0; m < 2; ++m)
        #pragma unroll
        for (int r = 0; r < 4; ++r)
          if (c < 4){
            int row = m*16 + (lane>>4)*4 + r;
            outHn[row*1024 + jw] = hyv[m][r];
            outCn[row*1024 + jw] = creg[m][r];
          }
    }
  }
}

// ---------------- host ----------------

extern "C" void kernel_launch(void* const* d_in, const int* in_sizes, int n_in,
                              void* d_out, int out_size, void* d_ws, size_t ws_size,
                              hipStream_t stream)
{
  const float* x    = (const float*)d_in[0];
  const float* h0   = (const float*)d_in[1];
  const float* c0   = (const float*)d_in[2];
  const float* Wih0 = (const float*)d_in[3];
  const float* Whh0 = (const float*)d_in[4];
  const float* bih0 = (const float*)d_in[5];
  const float* bhh0 = (const float*)d_in[6];
  const float* Wih1 = (const float*)d_in[7];
  const float* Whh1 = (const float*)d_in[8];
  const float* bih1 = (const float*)d_in[9];
  const float* bhh1 = (const float*)d_in[10];
  float* out = (float*)d_out;

  char* ws = (char*)d_ws;
  size_t off = 0;
  auto alloc = [&](size_t bytes)->char* {
    char* p = ws + off; off += (bytes + 255) & ~(size_t)255; return p;
  };
  unsigned short* Xf    = (unsigned short*)alloc((size_t)T_STEPS*65536);   // 32MB
  unsigned short* Ring0 = (unsigned short*)alloc((size_t)T_STEPS*65536);   // 32MB
  unsigned short* HiniF = (unsigned short*)alloc(2*65536);
  float* eps0 = (float*)alloc(T_STEPS*4);
  float* bias = (float*)alloc(2*4096*4);
  float* rs   = (float*)alloc(2*4096*4);
  unsigned* epsP = (unsigned*)alloc((size_t)T_STEPS*256*4);                // 512KB
  // flags: 2 layers x 64 blocks x 128B private lines
  char* sync  = alloc(64*128*2);
  unsigned* flag0 = (unsigned*)sync;
  unsigned* flag1 = (unsigned*)(sync + 64*128);
  // Ring1: prefer 512 unique slots (cached staging); fall back to 8 + bypass.
  size_t remain  = (off <= ws_size) ? (ws_size - off) : 0;
  int r1slots    = (remain >= (size_t)(T_STEPS+1)*65536) ? T_STEPS : 8;
  unsigned short* Ring1 = (unsigned short*)alloc((size_t)r1slots*65536);
  int r1mask   = r1slots - 1;
  int r1cached = (r1slots == T_STEPS) ? 1 : 0;
  if (off > ws_size)
    fprintf(stderr, "HardLSTM: ws too small, need %zu have %zu\n", off, ws_size);

  hipMemsetAsync(sync, 0, 64*128*2, stream);
  prep_xfrag<<<8192, 256, 0, stream>>>(x, Xf);
  prep_hfrag<<<32, 256, 0, stream>>>(h0, HiniF);
  reduce_mean_f32<<<T_STEPS, 256, 0, stream>>>(x, eps0, 1.0f);  // mean(x_t)+1
  prep_rs<<<2048, 256, 0, stream>>>(Wih0, Whh0, Wih1, Whh1,
                                    bih0, bhh0, bih1, bhh1, rs, bias);

  rec13<<<128, 256, 0, stream>>>(Xf, HiniF, Ring0, Ring1, r1mask, r1cached, out,
      Wih0, Whh0, Wih1, Whh1, bias, rs, eps0, c0, epsP, flag0, flag1);
}